// Round 4
// baseline (2412.915 us; speedup 1.0000x reference)
//
#include <hip/hip_runtime.h>
#include <hip/hip_bf16.h>
#include <math.h>

// Problem constants (MultiQueryAttention: B=2, S=2048, D=1024, H=16, hd=64)
#define BB 2
#define SS 2048
#define DD 1024
#define NH 16
#define HD 64
#define MM (BB * SS)  // 4096 tokens

typedef __hip_bfloat16 bf16;

// ---------------- runtime dtype detection ----------------
// flag==1 -> external tensors are fp32; flag==0 -> bf16.
// Discriminator: low 16 bits of each 32-bit word of x. If data is bf16, the
// low half IS a bf16 N(0,1) sample -> |v| in [2^-20, 64] (or 0) essentially
// always. If data is fp32, the low half is random mantissa bits -> uniform
// random exponent -> only ~10% land in that range.
__global__ void detect_dtype(const unsigned int* __restrict__ x, int* __restrict__ flag) {
    if (threadIdx.x == 0 && blockIdx.x == 0) {
        int good = 0;
        for (int i = 0; i < 256; i++) {
            unsigned int bits = (x[i] & 0xFFFFu) << 16;
            float v = __uint_as_float(bits);
            float av = fabsf(v);
            if (av == 0.f || (av >= 9.5367431640625e-7f && av <= 64.f)) good++;
        }
        *flag = (good >= 240) ? 0 : 1;
    }
}

__device__ __forceinline__ float loadAny(const void* p, size_t i, int isf32) {
    if (isf32) return ((const float*)p)[i];
    return __bfloat162float(((const bf16*)p)[i]);
}

// ---------------- generic tiled GEMM: C[M,N] = A[M,K] @ W[N,K]^T ----------------
// 64x64 tile, BK=16, 256 threads (16x16), 4x4 accumulators per thread, fp32 acc.
// outMode: 0 -> C written bf16 (internal ws tensors). 1 -> C dtype follows flag
// (fp32 when inputs are fp32, bf16 when inputs are bf16) — the external output.
#define GT 64
#define GBK 16

__global__ __launch_bounds__(256) void gemm_abt(const void* __restrict__ A,
                                                const void* __restrict__ W,
                                                void* __restrict__ C,
                                                int M, int N, int K,
                                                const int* __restrict__ flag,
                                                int aExt, int wExt, int outMode) {
    const int f = *flag;            // wave-uniform broadcast
    const int af = aExt ? f : 0;
    const int wf = wExt ? f : 0;
    const int of = outMode ? f : 0; // 1 -> store fp32

    __shared__ float As[GBK][GT + 1];
    __shared__ float Ws[GBK][GT + 1];

    const int tid = threadIdx.x;
    const int tx = tid & 15;        // col group
    const int ty = tid >> 4;        // row group
    const int rowBase = blockIdx.y * GT;
    const int colBase = blockIdx.x * GT;

    float acc[4][4] = {};

    for (int k0 = 0; k0 < K; k0 += GBK) {
#pragma unroll
        for (int i = 0; i < 4; i++) {
            int e = tid + 256 * i;
            int r = e >> 4;
            int c = e & 15;
            As[c][r] = loadAny(A, (size_t)(rowBase + r) * K + (k0 + c), af);
            Ws[c][r] = loadAny(W, (size_t)(colBase + r) * K + (k0 + c), wf);
        }
        __syncthreads();

#pragma unroll
        for (int k = 0; k < GBK; k++) {
            float a[4], b[4];
#pragma unroll
            for (int j = 0; j < 4; j++) a[j] = As[k][ty * 4 + j];
#pragma unroll
            for (int j = 0; j < 4; j++) b[j] = Ws[k][tx * 4 + j];
#pragma unroll
            for (int i = 0; i < 4; i++)
#pragma unroll
                for (int j = 0; j < 4; j++) acc[i][j] += a[i] * b[j];
        }
        __syncthreads();
    }

#pragma unroll
    for (int i = 0; i < 4; i++)
#pragma unroll
        for (int j = 0; j < 4; j++) {
            int r = rowBase + ty * 4 + i;
            int c = colBase + tx * 4 + j;
            if (r < M && c < N) {
                size_t idx = (size_t)r * N + c;
                if (of) ((float*)C)[idx] = acc[i][j];
                else    ((bf16*)C)[idx] = __float2bfloat16(acc[i][j]);
            }
        }
}

// ---------------- flash-style causal MQA attention ----------------
// Q: [M, D] bf16 (head h at cols h*64..h*64+63), K/V: [M, HD] bf16 (shared head).
// O aliases Q (in-place safe: each block reads exactly the disjoint Q region it
// later writes, once, into LDS, at block start).
#define TQ 16
#define TK 64

__global__ __launch_bounds__(256) void attn_kernel(const bf16* __restrict__ Q,
                                                   const bf16* __restrict__ K,
                                                   const bf16* __restrict__ V,
                                                   bf16* __restrict__ O) {
    const int qb = blockIdx.x;   // query tile
    const int h = blockIdx.y;    // head
    const int b = blockIdx.z;    // batch

    __shared__ float Qs[TQ][HD + 1];
    __shared__ float Ks[TK][HD + 1];
    __shared__ float Vs[TK][HD + 1];
    __shared__ float Sc[TQ][TK];
    __shared__ float mrow[TQ], lrow[TQ], arow[TQ];

    const int tid = threadIdx.x;
    const int qi0 = qb * TQ;
    const float scale = 0.125f;  // 1/sqrt(64)

    // Load Q tile (16 rows x 64 dims)
    const bf16* Qbase = Q + ((size_t)b * SS + qi0) * DD + h * HD;
    for (int e = tid; e < TQ * HD; e += 256) {
        int r = e >> 6;
        int c = e & 63;
        Qs[r][c] = __bfloat162float(Qbase[(size_t)r * DD + c]);
    }
    if (tid < TQ) {
        mrow[tid] = -INFINITY;
        lrow[tid] = 0.f;
    }

    float acc[4] = {0.f, 0.f, 0.f, 0.f};
    const int r4 = tid >> 4;          // query row this thread accumulates
    const int c4 = (tid & 15) * 4;    // 4 output dims this thread owns

    const int lastBlk = (qi0 + TQ - 1) / TK;  // inclusive causal limit

    for (int tb = 0; tb <= lastBlk; tb++) {
        __syncthreads();  // previous iteration's Sc/Vs reads done before overwrite

        const bf16* Kb = K + ((size_t)b * SS + tb * TK) * HD;
        const bf16* Vb = V + ((size_t)b * SS + tb * TK) * HD;
        for (int e = tid; e < TK * HD; e += 256) {
            int r = e >> 6;
            int c = e & 63;
            Ks[r][c] = __bfloat162float(Kb[(size_t)r * HD + c]);
            Vs[r][c] = __bfloat162float(Vb[(size_t)r * HD + c]);
        }
        __syncthreads();

        // Scores: 16x64, 4 per thread
#pragma unroll
        for (int i = 0; i < 4; i++) {
            int sidx = tid + 256 * i;
            int r = sidx >> 6;
            int t = sidx & 63;
            int kt = tb * TK + t;
            int qi = qi0 + r;
            float s;
            if (kt > qi) {
                s = -INFINITY;
            } else {
                s = 0.f;
#pragma unroll
                for (int d = 0; d < HD; d++) s += Qs[r][d] * Ks[t][d];
                s *= scale;
            }
            Sc[r][t] = s;
        }
        __syncthreads();

        // Online softmax per query row (16 threads active)
        if (tid < TQ) {
            int r = tid;
            float m = mrow[r];
            float mnew = m;
            for (int t = 0; t < TK; t++) mnew = fmaxf(mnew, Sc[r][t]);
            float a, lsum = 0.f;
            if (mnew == -INFINITY) {
                a = 1.f;
                for (int t = 0; t < TK; t++) Sc[r][t] = 0.f;
            } else {
                a = (m == -INFINITY) ? 0.f : expf(m - mnew);
                for (int t = 0; t < TK; t++) {
                    float p = expf(Sc[r][t] - mnew);  // exp(-inf) = 0 handles mask
                    Sc[r][t] = p;
                    lsum += p;
                }
            }
            mrow[r] = mnew;
            lrow[r] = lrow[r] * a + lsum;
            arow[r] = a;
        }
        __syncthreads();

        // Accumulate P @ V for this tile
        float al = arow[r4];
#pragma unroll
        for (int j = 0; j < 4; j++) acc[j] *= al;
        for (int t = 0; t < TK; t++) {
            float p = Sc[r4][t];
#pragma unroll
            for (int j = 0; j < 4; j++) acc[j] += p * Vs[t][c4 + j];
        }
    }

    // Epilogue: normalize and write (in-place over this block's own Q region)
    float l = lrow[r4];
    float inv = (l > 0.f) ? 1.f / l : 0.f;
    bf16* Ob = O + ((size_t)b * SS + qi0 + r4) * DD + h * HD + c4;
#pragma unroll
    for (int j = 0; j < 4; j++) Ob[j] = __float2bfloat16(acc[j] * inv);
}

// ---------------- launch ----------------
extern "C" void kernel_launch(void* const* d_in, const int* in_sizes, int n_in,
                              void* d_out, int out_size, void* d_ws, size_t ws_size,
                              hipStream_t stream) {
    const void* x  = d_in[0];
    const void* Wq = d_in[1];
    const void* Wk = d_in[2];
    const void* Wv = d_in[3];
    const void* Wo = d_in[4];
    // d_in[5] = causal mask — known tril, handled analytically in attn_kernel.

    // Workspace layout (~9.0 MB):
    //   [flag 256B] | QA bf16[4096,1024] (Q, overwritten in-place by attention
    //   output) | K bf16[4096,64] | V bf16[4096,64]
    char* ws = (char*)d_ws;
    int* flag = (int*)ws;
    bf16* QA = (bf16*)(ws + 256);
    bf16* Kp = QA + (size_t)MM * DD;
    bf16* Vp = Kp + (size_t)MM * HD;

    dim3 blk(256);

    detect_dtype<<<1, 64, 0, stream>>>((const unsigned int*)x, flag);

    // Projections: q = x@Wq^T, k = x@Wk^T, v = x@Wv^T  (bf16 intermediates)
    gemm_abt<<<dim3(DD / GT, MM / GT), blk, 0, stream>>>(x, Wq, QA, MM, DD, DD, flag, 1, 1, 0);
    gemm_abt<<<dim3(HD / GT, MM / GT), blk, 0, stream>>>(x, Wk, Kp, MM, HD, DD, flag, 1, 1, 0);
    gemm_abt<<<dim3(HD / GT, MM / GT), blk, 0, stream>>>(x, Wv, Vp, MM, HD, DD, flag, 1, 1, 0);

    // Causal MQA attention (writes in-place over QA)
    attn_kernel<<<dim3(SS / TQ, NH, BB), blk, 0, stream>>>(QA, Kp, Vp, QA);

    // Output projection: out = AO @ Wo^T — output dtype follows detected world
    // (fp32 inputs -> fp32 out, bf16 inputs -> bf16 out)
    gemm_abt<<<dim3(DD / GT, MM / GT), blk, 0, stream>>>(QA, Wo, d_out, MM, DD, DD, flag, 0, 1, 1);
}

// Round 5
// 950.689 us; speedup vs baseline: 2.5381x; 2.5381x over previous
//
#include <hip/hip_runtime.h>
#include <hip/hip_bf16.h>
#include <math.h>

// Problem constants (MultiQueryAttention: B=2, S=2048, D=1024, H=16, hd=64)
#define BB 2
#define SS 2048
#define DD 1024
#define NH 16
#define HD 64
#define MM (BB * SS)  // 4096 tokens

typedef __hip_bfloat16 bf16;      // storage type for ws tensors
typedef __bf16 bf16_t;            // native compiler bf16 (same 2-byte layout)
typedef __attribute__((ext_vector_type(8))) __bf16 bf16x8;
typedef __attribute__((ext_vector_type(4))) float floatx4;

// ---------------- runtime dtype detection ----------------
// flag==1 -> external tensors are fp32; flag==0 -> bf16. (Round 4 proved fp32,
// but keep the detector as insurance; it is provably discriminating.)
__global__ void detect_dtype(const unsigned int* __restrict__ x, int* __restrict__ flag) {
    if (threadIdx.x == 0 && blockIdx.x == 0) {
        int good = 0;
        for (int i = 0; i < 256; i++) {
            unsigned int bits = (x[i] & 0xFFFFu) << 16;
            float v = __uint_as_float(bits);
            float av = fabsf(v);
            if (av == 0.f || (av >= 9.5367431640625e-7f && av <= 64.f)) good++;
        }
        *flag = (good >= 240) ? 0 : 1;
    }
}

__device__ __forceinline__ float loadAny(const void* p, size_t i, int isf32) {
    if (isf32) return ((const float*)p)[i];
    return __bfloat162float(((const bf16*)p)[i]);
}

// ---------------- generic tiled GEMM: C[M,N] = A[M,K] @ W[N,K]^T ----------------
// (unchanged from round 4 — known correct; MFMA conversion is next round)
#define GT 64
#define GBK 16

__global__ __launch_bounds__(256) void gemm_abt(const void* __restrict__ A,
                                                const void* __restrict__ W,
                                                void* __restrict__ C,
                                                int M, int N, int K,
                                                const int* __restrict__ flag,
                                                int aExt, int wExt, int outMode) {
    const int f = *flag;
    const int af = aExt ? f : 0;
    const int wf = wExt ? f : 0;
    const int of = outMode ? f : 0;

    __shared__ float As[GBK][GT + 1];
    __shared__ float Ws[GBK][GT + 1];

    const int tid = threadIdx.x;
    const int tx = tid & 15;
    const int ty = tid >> 4;
    const int rowBase = blockIdx.y * GT;
    const int colBase = blockIdx.x * GT;

    float acc[4][4] = {};

    for (int k0 = 0; k0 < K; k0 += GBK) {
#pragma unroll
        for (int i = 0; i < 4; i++) {
            int e = tid + 256 * i;
            int r = e >> 4;
            int c = e & 15;
            As[c][r] = loadAny(A, (size_t)(rowBase + r) * K + (k0 + c), af);
            Ws[c][r] = loadAny(W, (size_t)(colBase + r) * K + (k0 + c), wf);
        }
        __syncthreads();

#pragma unroll
        for (int k = 0; k < GBK; k++) {
            float a[4], b[4];
#pragma unroll
            for (int j = 0; j < 4; j++) a[j] = As[k][ty * 4 + j];
#pragma unroll
            for (int j = 0; j < 4; j++) b[j] = Ws[k][tx * 4 + j];
#pragma unroll
            for (int i = 0; i < 4; i++)
#pragma unroll
                for (int j = 0; j < 4; j++) acc[i][j] += a[i] * b[j];
        }
        __syncthreads();
    }

#pragma unroll
    for (int i = 0; i < 4; i++)
#pragma unroll
        for (int j = 0; j < 4; j++) {
            int r = rowBase + ty * 4 + i;
            int c = colBase + tx * 4 + j;
            if (r < M && c < N) {
                size_t idx = (size_t)r * N + c;
                if (of) ((float*)C)[idx] = acc[i][j];
                else    ((bf16*)C)[idx] = __float2bfloat16(acc[i][j]);
            }
        }
}

// ---------------- MFMA flash-style causal MQA attention ----------------
// Block = 4 waves; each wave owns 16 query rows (block covers 64) of one (b,h).
// K-tiles of 64 keys, online softmax, P round-trips through LDS (C-layout ->
// A-layout), V staged transposed. O written in-place over Q (disjoint regions).
//
// mfma_f32_16x16x32_bf16 layouts (HW-verified per guide):
//   A[m = lane&15][k = (lane>>4)*8 + j]   (8 bf16 / lane)
//   B[n = lane&15][k = (lane>>4)*8 + j]
//   C/D: col = lane&15, row = (lane>>4)*4 + reg
#define LDP 72                    // padded LDS row stride (bf16 elems), 144 B
#define ALOG2E 0.18033688011112042f  // (1/sqrt(64)) * log2(e)

__global__ __launch_bounds__(256) void attn_mfma(const bf16_t* Q,
                                                 const bf16_t* __restrict__ K,
                                                 const bf16_t* __restrict__ V,
                                                 bf16_t* O) {
    const int qb = blockIdx.x;   // 64-row query tile
    const int h  = blockIdx.y;
    const int b  = blockIdx.z;
    const int q0 = qb * 64;

    const int tid  = threadIdx.x;
    const int wq   = tid >> 6;     // wave id -> query sub-tile
    const int lane = tid & 63;
    const int lo   = lane & 15;
    const int quad = lane >> 4;

    __shared__ bf16_t Ks[64 * LDP];        // K-tile  [key][dim]
    __shared__ bf16_t Vt[64 * LDP];        // V-tile transposed [dim][key]
    __shared__ bf16_t Ps[4 * 16 * LDP];    // P per wave [qrow][key]

    // Q fragments (A operand), loaded once: row = lo, dim = kc*32 + quad*8 + j
    const bf16_t* Qrow = Q + ((size_t)(b * SS + q0 + wq * 16 + lo)) * DD + h * HD;
    const bf16x8 qf0 = *(const bf16x8*)(Qrow + quad * 8);
    const bf16x8 qf1 = *(const bf16x8*)(Qrow + 32 + quad * 8);

    floatx4 Oacc[4];
    float m_i[4], l_i[4];
#pragma unroll
    for (int nb = 0; nb < 4; nb++) Oacc[nb] = (floatx4){0.f, 0.f, 0.f, 0.f};
#pragma unroll
    for (int r = 0; r < 4; r++) { m_i[r] = -1e30f; l_i[r] = 0.f; }

    const bf16_t* Kb0 = K + (size_t)(b * SS) * HD;
    const bf16_t* Vb0 = V + (size_t)(b * SS) * HD;
    const int lastTb = q0 >> 6;

    for (int tb = 0; tb <= lastTb; tb++) {
        __syncthreads();  // prior tile's LDS reads complete before overwrite

        // ---- stage K tile: 64 keys x 64 dims, padded rows, coalesced 16B ----
        const bf16_t* Kg = Kb0 + (size_t)tb * 64 * HD;
        const bf16_t* Vg = Vb0 + (size_t)tb * 64 * HD;
#pragma unroll
        for (int p = 0; p < 2; p++) {
            int chunk = tid + 256 * p;       // 512 chunks of 8 bf16
            int key = chunk >> 3, seg = chunk & 7;
            *(bf16x8*)&Ks[key * LDP + seg * 8] = *(const bf16x8*)(Kg + key * HD + seg * 8);
        }
        // ---- stage V transposed: Vt[dim][key] ----
#pragma unroll
        for (int p = 0; p < 2; p++) {
            int dimseg = (tid >> 6) + 4 * p;  // 0..7
            int key = tid & 63;
            bf16x8 vv = *(const bf16x8*)(Vg + key * HD + dimseg * 8);
#pragma unroll
            for (int j = 0; j < 8; j++) Vt[(dimseg * 8 + j) * LDP + key] = vv[j];
        }
        __syncthreads();

        // ---- QK^T: 16 q-rows x 64 keys per wave ----
        floatx4 sc[4];
#pragma unroll
        for (int nb = 0; nb < 4; nb++) {
            const bf16x8 kf0 = *(const bf16x8*)&Ks[(nb * 16 + lo) * LDP + quad * 8];
            const bf16x8 kf1 = *(const bf16x8*)&Ks[(nb * 16 + lo) * LDP + 32 + quad * 8];
            floatx4 z = (floatx4){0.f, 0.f, 0.f, 0.f};
            z = __builtin_amdgcn_mfma_f32_16x16x32_bf16(qf0, kf0, z, 0, 0, 0);
            z = __builtin_amdgcn_mfma_f32_16x16x32_bf16(qf1, kf1, z, 0, 0, 0);
            sc[nb] = z;
        }

        // ---- causal mask (diagonal tile only; uniform branch) ----
        if (tb == lastTb) {
            const int rowg = q0 + wq * 16 + quad * 4;
            const int keyg = tb * 64 + lo;
#pragma unroll
            for (int nb = 0; nb < 4; nb++)
#pragma unroll
                for (int reg = 0; reg < 4; reg++)
                    if (keyg + nb * 16 > rowg + reg) sc[nb][reg] = -1e30f;
        }

        // ---- online softmax (raw-dot units; scale folded into exp2) ----
        float al[4], rs[4];
#pragma unroll
        for (int reg = 0; reg < 4; reg++) {
            float v = fmaxf(fmaxf(sc[0][reg], sc[1][reg]), fmaxf(sc[2][reg], sc[3][reg]));
#pragma unroll
            for (int s = 1; s < 16; s <<= 1) v = fmaxf(v, __shfl_xor(v, s));
            float mn = fmaxf(m_i[reg], v);
            al[reg] = exp2f((m_i[reg] - mn) * ALOG2E);
            m_i[reg] = mn;
            rs[reg] = 0.f;
        }
        bf16_t* Pw = &Ps[wq * 16 * LDP];
#pragma unroll
        for (int nb = 0; nb < 4; nb++)
#pragma unroll
            for (int reg = 0; reg < 4; reg++) {
                float p = exp2f((sc[nb][reg] - m_i[reg]) * ALOG2E);
                rs[reg] += p;
                Pw[(quad * 4 + reg) * LDP + nb * 16 + lo] = (bf16_t)p;
            }
#pragma unroll
        for (int reg = 0; reg < 4; reg++) {
            float v = rs[reg];
#pragma unroll
            for (int s = 1; s < 16; s <<= 1) v += __shfl_xor(v, s);
            l_i[reg] = l_i[reg] * al[reg] + v;
#pragma unroll
            for (int nb = 0; nb < 4; nb++) Oacc[nb][reg] *= al[reg];
        }
        __syncthreads();  // P (C-layout) visible before A-layout re-read

        // ---- P @ V ----
        const bf16x8 af0 = *(const bf16x8*)&Pw[lo * LDP + quad * 8];
        const bf16x8 af1 = *(const bf16x8*)&Pw[lo * LDP + 32 + quad * 8];
#pragma unroll
        for (int nb = 0; nb < 4; nb++) {
            const bf16x8 vf0 = *(const bf16x8*)&Vt[(nb * 16 + lo) * LDP + quad * 8];
            const bf16x8 vf1 = *(const bf16x8*)&Vt[(nb * 16 + lo) * LDP + 32 + quad * 8];
            Oacc[nb] = __builtin_amdgcn_mfma_f32_16x16x32_bf16(af0, vf0, Oacc[nb], 0, 0, 0);
            Oacc[nb] = __builtin_amdgcn_mfma_f32_16x16x32_bf16(af1, vf1, Oacc[nb], 0, 0, 0);
        }
    }

    // ---- epilogue: normalize, write in-place over this block's Q region ----
#pragma unroll
    for (int reg = 0; reg < 4; reg++) {
        float inv = 1.f / l_i[reg];
        bf16_t* Orow = O + ((size_t)(b * SS + q0 + wq * 16 + quad * 4 + reg)) * DD + h * HD;
#pragma unroll
        for (int nb = 0; nb < 4; nb++)
            Orow[nb * 16 + lo] = (bf16_t)(Oacc[nb][reg] * inv);
    }
}

// ---------------- launch ----------------
extern "C" void kernel_launch(void* const* d_in, const int* in_sizes, int n_in,
                              void* d_out, int out_size, void* d_ws, size_t ws_size,
                              hipStream_t stream) {
    const void* x  = d_in[0];
    const void* Wq = d_in[1];
    const void* Wk = d_in[2];
    const void* Wv = d_in[3];
    const void* Wo = d_in[4];
    // d_in[5] = causal mask — known tril, handled analytically in attn_mfma.

    // Workspace (~9.0 MB): [flag 256B] | QA bf16[4096,1024] (Q -> attention
    // output in-place) | K bf16[4096,64] | V bf16[4096,64]
    char* ws = (char*)d_ws;
    int* flag = (int*)ws;
    bf16* QA = (bf16*)(ws + 256);
    bf16* Kp = QA + (size_t)MM * DD;
    bf16* Vp = Kp + (size_t)MM * HD;

    dim3 blk(256);

    detect_dtype<<<1, 64, 0, stream>>>((const unsigned int*)x, flag);

    // Projections (bf16 intermediates)
    gemm_abt<<<dim3(DD / GT, MM / GT), blk, 0, stream>>>(x, Wq, QA, MM, DD, DD, flag, 1, 1, 0);
    gemm_abt<<<dim3(HD / GT, MM / GT), blk, 0, stream>>>(x, Wk, Kp, MM, HD, DD, flag, 1, 1, 0);
    gemm_abt<<<dim3(HD / GT, MM / GT), blk, 0, stream>>>(x, Wv, Vp, MM, HD, DD, flag, 1, 1, 0);

    // MFMA causal MQA attention (in-place over QA)
    attn_mfma<<<dim3(SS / 64, NH, BB), blk, 0, stream>>>(
        (const bf16_t*)QA, (const bf16_t*)Kp, (const bf16_t*)Vp, (bf16_t*)QA);

    // Output projection — dtype follows detected world (fp32 out here)
    gemm_abt<<<dim3(DD / GT, MM / GT), blk, 0, stream>>>(QA, Wo, d_out, MM, DD, DD, flag, 0, 1, 1);
}

// Round 6
// 369.397 us; speedup vs baseline: 6.5320x; 2.5736x over previous
//
#include <hip/hip_runtime.h>
#include <hip/hip_bf16.h>
#include <math.h>

// Problem constants (MultiQueryAttention: B=2, S=2048, D=1024, H=16, hd=64)
#define BB 2
#define SS 2048
#define DD 1024
#define NH 16
#define HD 64
#define MM (BB * SS)  // 4096 tokens

typedef __hip_bfloat16 bf16;      // storage type for ws tensors
typedef __bf16 bf16_t;            // native compiler bf16
typedef __attribute__((ext_vector_type(8))) __bf16 bf16x8;
typedef __attribute__((ext_vector_type(4))) __bf16 bf16x4;
typedef __attribute__((ext_vector_type(4))) float floatx4;

// ---------------- runtime dtype detection ----------------
// flag==1 -> external tensors are fp32 (the proven world); flag==0 -> bf16.
__global__ void detect_dtype(const unsigned int* __restrict__ x, int* __restrict__ flag) {
    if (threadIdx.x == 0 && blockIdx.x == 0) {
        int good = 0;
        for (int i = 0; i < 256; i++) {
            unsigned int bits = (x[i] & 0xFFFFu) << 16;
            float v = __uint_as_float(bits);
            float av = fabsf(v);
            if (av == 0.f || (av >= 9.5367431640625e-7f && av <= 64.f)) good++;
        }
        *flag = (good >= 240) ? 0 : 1;
    }
}

// ---------------- MFMA projection GEMMs ----------------
// 128x128 tile, BK=32, 4 waves (2x2), 16 mfma_f32_16x16x32_bf16 per K-iter.
// Fragment layouts (HW-validated by round-5 attention kernel):
//   A[m=lane&15][k=(lane>>4)*8+j], B[n=lane&15][k=(lane>>4)*8+j]
//   C/D: col=lane&15, row=(lane>>4)*4+reg
#define BK 32
#define KP 40   // LDS row stride in bf16 elems (80 B = 5x16 B; 2-way alias only)

// Fused QKV projection: out cols 0..1023 -> QA, col-block 8 -> Kp (0..63) / Vp.
__global__ __launch_bounds__(256) void proj_qkv(const void* __restrict__ X,
                                                const void* __restrict__ Wq,
                                                const void* __restrict__ Wk,
                                                const void* __restrict__ Wv,
                                                bf16_t* __restrict__ QA,
                                                bf16_t* __restrict__ Kp,
                                                bf16_t* __restrict__ Vp,
                                                const int* __restrict__ flag) {
    const int f = *flag;  // 1 => fp32 inputs

    __shared__ bf16_t As[128 * KP];
    __shared__ bf16_t Ws[128 * KP];

    const int tid = threadIdx.x;
    const int wave = tid >> 6, lane = tid & 63;
    const int lo = lane & 15, quad = lane >> 4;
    const int wr = wave >> 1, wc = wave & 1;
    const int cb = blockIdx.x;              // 0..8 (8 = KV block)
    const int rowBase = blockIdx.y * 128;

    floatx4 acc[4][4];
#pragma unroll
    for (int i = 0; i < 4; i++)
#pragma unroll
        for (int j = 0; j < 4; j++) acc[i][j] = (floatx4){0.f, 0.f, 0.f, 0.f};

    for (int k0 = 0; k0 < DD; k0 += BK) {
        // ---- stage A (x) 128x32 -> bf16 LDS ----
        if (f) {
#pragma unroll
            for (int p = 0; p < 4; p++) {
                int chunk = tid + 256 * p;
                int row = chunk >> 3, seg = chunk & 7;
                float4 v = *(const float4*)((const float*)X +
                                            (size_t)(rowBase + row) * DD + k0 + seg * 4);
                bf16x4 o;
                o[0] = (bf16_t)v.x; o[1] = (bf16_t)v.y; o[2] = (bf16_t)v.z; o[3] = (bf16_t)v.w;
                *(bf16x4*)&As[row * KP + seg * 4] = o;
            }
        } else {
#pragma unroll
            for (int p = 0; p < 2; p++) {
                int chunk = tid + 256 * p;
                int row = chunk >> 2, seg = chunk & 3;
                *(bf16x8*)&As[row * KP + seg * 8] =
                    *(const bf16x8*)((const bf16_t*)X + (size_t)(rowBase + row) * DD + k0 + seg * 8);
            }
        }
        // ---- stage W tile (rows = output cols cb*128 .. +127) ----
        if (f) {
#pragma unroll
            for (int p = 0; p < 4; p++) {
                int chunk = tid + 256 * p;
                int row = chunk >> 3, seg = chunk & 7;
                const float* wsrc;
                if (cb < 8)        wsrc = (const float*)Wq + (size_t)(cb * 128 + row) * DD;
                else if (row < 64) wsrc = (const float*)Wk + (size_t)row * DD;
                else               wsrc = (const float*)Wv + (size_t)(row - 64) * DD;
                float4 v = *(const float4*)(wsrc + k0 + seg * 4);
                bf16x4 o;
                o[0] = (bf16_t)v.x; o[1] = (bf16_t)v.y; o[2] = (bf16_t)v.z; o[3] = (bf16_t)v.w;
                *(bf16x4*)&Ws[row * KP + seg * 4] = o;
            }
        } else {
#pragma unroll
            for (int p = 0; p < 2; p++) {
                int chunk = tid + 256 * p;
                int row = chunk >> 2, seg = chunk & 3;
                const bf16_t* wsrc;
                if (cb < 8)        wsrc = (const bf16_t*)Wq + (size_t)(cb * 128 + row) * DD;
                else if (row < 64) wsrc = (const bf16_t*)Wk + (size_t)row * DD;
                else               wsrc = (const bf16_t*)Wv + (size_t)(row - 64) * DD;
                *(bf16x8*)&Ws[row * KP + seg * 8] = *(const bf16x8*)(wsrc + k0 + seg * 8);
            }
        }
        __syncthreads();

        bf16x8 afr[4], bfr[4];
#pragma unroll
        for (int i = 0; i < 4; i++)
            afr[i] = *(const bf16x8*)&As[(wr * 64 + i * 16 + lo) * KP + quad * 8];
#pragma unroll
        for (int j = 0; j < 4; j++)
            bfr[j] = *(const bf16x8*)&Ws[(wc * 64 + j * 16 + lo) * KP + quad * 8];
#pragma unroll
        for (int i = 0; i < 4; i++)
#pragma unroll
            for (int j = 0; j < 4; j++)
                acc[i][j] = __builtin_amdgcn_mfma_f32_16x16x32_bf16(afr[i], bfr[j], acc[i][j], 0, 0, 0);
        __syncthreads();
    }

    // ---- epilogue ----
#pragma unroll
    for (int i = 0; i < 4; i++)
#pragma unroll
        for (int j = 0; j < 4; j++)
#pragma unroll
            for (int reg = 0; reg < 4; reg++) {
                int row = rowBase + wr * 64 + i * 16 + quad * 4 + reg;
                int col = wc * 64 + j * 16 + lo;  // 0..127 within col-block
                bf16_t val = (bf16_t)acc[i][j][reg];
                if (cb < 8)         QA[(size_t)row * DD + cb * 128 + col] = val;
                else if (col < 64)  Kp[(size_t)row * HD + col] = val;
                else                Vp[(size_t)row * HD + (col - 64)] = val;
            }
}

// Output projection: C[M,DD] = AO[M,DD](bf16) @ Wo[DD,DD]^T, out dtype per flag.
__global__ __launch_bounds__(256) void proj_o(const bf16_t* __restrict__ AO,
                                              const void* __restrict__ Wo,
                                              void* __restrict__ Cout,
                                              const int* __restrict__ flag) {
    const int f = *flag;

    __shared__ bf16_t As[128 * KP];
    __shared__ bf16_t Ws[128 * KP];

    const int tid = threadIdx.x;
    const int wave = tid >> 6, lane = tid & 63;
    const int lo = lane & 15, quad = lane >> 4;
    const int wr = wave >> 1, wc = wave & 1;
    const int colBase = blockIdx.x * 128;
    const int rowBase = blockIdx.y * 128;

    floatx4 acc[4][4];
#pragma unroll
    for (int i = 0; i < 4; i++)
#pragma unroll
        for (int j = 0; j < 4; j++) acc[i][j] = (floatx4){0.f, 0.f, 0.f, 0.f};

    for (int k0 = 0; k0 < DD; k0 += BK) {
        // A: always bf16 (ws intermediate)
#pragma unroll
        for (int p = 0; p < 2; p++) {
            int chunk = tid + 256 * p;
            int row = chunk >> 2, seg = chunk & 3;
            *(bf16x8*)&As[row * KP + seg * 8] =
                *(const bf16x8*)(AO + (size_t)(rowBase + row) * DD + k0 + seg * 8);
        }
        // W: flag-dispatched
        if (f) {
#pragma unroll
            for (int p = 0; p < 4; p++) {
                int chunk = tid + 256 * p;
                int row = chunk >> 3, seg = chunk & 7;
                float4 v = *(const float4*)((const float*)Wo +
                                            (size_t)(colBase + row) * DD + k0 + seg * 4);
                bf16x4 o;
                o[0] = (bf16_t)v.x; o[1] = (bf16_t)v.y; o[2] = (bf16_t)v.z; o[3] = (bf16_t)v.w;
                *(bf16x4*)&Ws[row * KP + seg * 4] = o;
            }
        } else {
#pragma unroll
            for (int p = 0; p < 2; p++) {
                int chunk = tid + 256 * p;
                int row = chunk >> 2, seg = chunk & 3;
                *(bf16x8*)&Ws[row * KP + seg * 8] =
                    *(const bf16x8*)((const bf16_t*)Wo + (size_t)(colBase + row) * DD + k0 + seg * 8);
            }
        }
        __syncthreads();

        bf16x8 afr[4], bfr[4];
#pragma unroll
        for (int i = 0; i < 4; i++)
            afr[i] = *(const bf16x8*)&As[(wr * 64 + i * 16 + lo) * KP + quad * 8];
#pragma unroll
        for (int j = 0; j < 4; j++)
            bfr[j] = *(const bf16x8*)&Ws[(wc * 64 + j * 16 + lo) * KP + quad * 8];
#pragma unroll
        for (int i = 0; i < 4; i++)
#pragma unroll
            for (int j = 0; j < 4; j++)
                acc[i][j] = __builtin_amdgcn_mfma_f32_16x16x32_bf16(afr[i], bfr[j], acc[i][j], 0, 0, 0);
        __syncthreads();
    }

#pragma unroll
    for (int i = 0; i < 4; i++)
#pragma unroll
        for (int j = 0; j < 4; j++)
#pragma unroll
            for (int reg = 0; reg < 4; reg++) {
                int row = rowBase + wr * 64 + i * 16 + quad * 4 + reg;
                int col = colBase + wc * 64 + j * 16 + lo;
                size_t idx = (size_t)row * DD + col;
                if (f) ((float*)Cout)[idx] = acc[i][j][reg];
                else   ((bf16_t*)Cout)[idx] = (bf16_t)acc[i][j][reg];
            }
}

// ---------------- MFMA flash-style causal MQA attention (round-5, validated) ----
#define LDP 72                        // padded LDS row stride (bf16 elems)
#define ALOG2E 0.18033688011112042f   // (1/sqrt(64)) * log2(e)

__global__ __launch_bounds__(256) void attn_mfma(const bf16_t* Q,
                                                 const bf16_t* __restrict__ K,
                                                 const bf16_t* __restrict__ V,
                                                 bf16_t* O) {
    const int qb = blockIdx.x;
    const int h  = blockIdx.y;
    const int b  = blockIdx.z;
    const int q0 = qb * 64;

    const int tid  = threadIdx.x;
    const int wq   = tid >> 6;
    const int lane = tid & 63;
    const int lo   = lane & 15;
    const int quad = lane >> 4;

    __shared__ bf16_t Ks[64 * LDP];
    __shared__ bf16_t Vt[64 * LDP];
    __shared__ bf16_t Ps[4 * 16 * LDP];

    const bf16_t* Qrow = Q + ((size_t)(b * SS + q0 + wq * 16 + lo)) * DD + h * HD;
    const bf16x8 qf0 = *(const bf16x8*)(Qrow + quad * 8);
    const bf16x8 qf1 = *(const bf16x8*)(Qrow + 32 + quad * 8);

    floatx4 Oacc[4];
    float m_i[4], l_i[4];
#pragma unroll
    for (int nb = 0; nb < 4; nb++) Oacc[nb] = (floatx4){0.f, 0.f, 0.f, 0.f};
#pragma unroll
    for (int r = 0; r < 4; r++) { m_i[r] = -1e30f; l_i[r] = 0.f; }

    const bf16_t* Kb0 = K + (size_t)(b * SS) * HD;
    const bf16_t* Vb0 = V + (size_t)(b * SS) * HD;
    const int lastTb = q0 >> 6;

    for (int tb = 0; tb <= lastTb; tb++) {
        __syncthreads();

        const bf16_t* Kg = Kb0 + (size_t)tb * 64 * HD;
        const bf16_t* Vg = Vb0 + (size_t)tb * 64 * HD;
#pragma unroll
        for (int p = 0; p < 2; p++) {
            int chunk = tid + 256 * p;
            int key = chunk >> 3, seg = chunk & 7;
            *(bf16x8*)&Ks[key * LDP + seg * 8] = *(const bf16x8*)(Kg + key * HD + seg * 8);
        }
#pragma unroll
        for (int p = 0; p < 2; p++) {
            int dimseg = (tid >> 6) + 4 * p;
            int key = tid & 63;
            bf16x8 vv = *(const bf16x8*)(Vg + key * HD + dimseg * 8);
#pragma unroll
            for (int j = 0; j < 8; j++) Vt[(dimseg * 8 + j) * LDP + key] = vv[j];
        }
        __syncthreads();

        floatx4 sc[4];
#pragma unroll
        for (int nb = 0; nb < 4; nb++) {
            const bf16x8 kf0 = *(const bf16x8*)&Ks[(nb * 16 + lo) * LDP + quad * 8];
            const bf16x8 kf1 = *(const bf16x8*)&Ks[(nb * 16 + lo) * LDP + 32 + quad * 8];
            floatx4 z = (floatx4){0.f, 0.f, 0.f, 0.f};
            z = __builtin_amdgcn_mfma_f32_16x16x32_bf16(qf0, kf0, z, 0, 0, 0);
            z = __builtin_amdgcn_mfma_f32_16x16x32_bf16(qf1, kf1, z, 0, 0, 0);
            sc[nb] = z;
        }

        if (tb == lastTb) {
            const int rowg = q0 + wq * 16 + quad * 4;
            const int keyg = tb * 64 + lo;
#pragma unroll
            for (int nb = 0; nb < 4; nb++)
#pragma unroll
                for (int reg = 0; reg < 4; reg++)
                    if (keyg + nb * 16 > rowg + reg) sc[nb][reg] = -1e30f;
        }

        float al[4], rs[4];
#pragma unroll
        for (int reg = 0; reg < 4; reg++) {
            float v = fmaxf(fmaxf(sc[0][reg], sc[1][reg]), fmaxf(sc[2][reg], sc[3][reg]));
#pragma unroll
            for (int s = 1; s < 16; s <<= 1) v = fmaxf(v, __shfl_xor(v, s));
            float mn = fmaxf(m_i[reg], v);
            al[reg] = exp2f((m_i[reg] - mn) * ALOG2E);
            m_i[reg] = mn;
            rs[reg] = 0.f;
        }
        bf16_t* Pw = &Ps[wq * 16 * LDP];
#pragma unroll
        for (int nb = 0; nb < 4; nb++)
#pragma unroll
            for (int reg = 0; reg < 4; reg++) {
                float p = exp2f((sc[nb][reg] - m_i[reg]) * ALOG2E);
                rs[reg] += p;
                Pw[(quad * 4 + reg) * LDP + nb * 16 + lo] = (bf16_t)p;
            }
#pragma unroll
        for (int reg = 0; reg < 4; reg++) {
            float v = rs[reg];
#pragma unroll
            for (int s = 1; s < 16; s <<= 1) v += __shfl_xor(v, s);
            l_i[reg] = l_i[reg] * al[reg] + v;
#pragma unroll
            for (int nb = 0; nb < 4; nb++) Oacc[nb][reg] *= al[reg];
        }
        __syncthreads();

        const bf16x8 af0 = *(const bf16x8*)&Pw[lo * LDP + quad * 8];
        const bf16x8 af1 = *(const bf16x8*)&Pw[lo * LDP + 32 + quad * 8];
#pragma unroll
        for (int nb = 0; nb < 4; nb++) {
            const bf16x8 vf0 = *(const bf16x8*)&Vt[(nb * 16 + lo) * LDP + quad * 8];
            const bf16x8 vf1 = *(const bf16x8*)&Vt[(nb * 16 + lo) * LDP + 32 + quad * 8];
            Oacc[nb] = __builtin_amdgcn_mfma_f32_16x16x32_bf16(af0, vf0, Oacc[nb], 0, 0, 0);
            Oacc[nb] = __builtin_amdgcn_mfma_f32_16x16x32_bf16(af1, vf1, Oacc[nb], 0, 0, 0);
        }
    }

#pragma unroll
    for (int reg = 0; reg < 4; reg++) {
        float inv = 1.f / l_i[reg];
        bf16_t* Orow = O + ((size_t)(b * SS + q0 + wq * 16 + quad * 4 + reg)) * DD + h * HD;
#pragma unroll
        for (int nb = 0; nb < 4; nb++)
            Orow[nb * 16 + lo] = (bf16_t)(Oacc[nb][reg] * inv);
    }
}

// ---------------- launch ----------------
extern "C" void kernel_launch(void* const* d_in, const int* in_sizes, int n_in,
                              void* d_out, int out_size, void* d_ws, size_t ws_size,
                              hipStream_t stream) {
    const void* x  = d_in[0];
    const void* Wq = d_in[1];
    const void* Wk = d_in[2];
    const void* Wv = d_in[3];
    const void* Wo = d_in[4];
    // d_in[5] = causal mask — known tril, handled analytically in attn_mfma.

    // Workspace (~9.0 MB): [flag 256B] | QA bf16[4096,1024] (Q -> attention
    // output in-place) | K bf16[4096,64] | V bf16[4096,64]
    char* ws = (char*)d_ws;
    int* flag = (int*)ws;
    bf16_t* QA = (bf16_t*)(ws + 256);
    bf16_t* Kp = QA + (size_t)MM * DD;
    bf16_t* Vp = Kp + (size_t)MM * HD;

    detect_dtype<<<1, 64, 0, stream>>>((const unsigned int*)x, flag);

    // Fused Q/K/V projection (MFMA): 9 col-blocks x 32 row-blocks
    proj_qkv<<<dim3(9, MM / 128), dim3(256), 0, stream>>>(x, Wq, Wk, Wv, QA, Kp, Vp, flag);

    // MFMA causal MQA attention (in-place over QA)
    attn_mfma<<<dim3(SS / 64, NH, BB), dim3(256), 0, stream>>>(QA, Kp, Vp, QA);

    // Output projection (MFMA), out dtype per flag (fp32 here)
    proj_o<<<dim3(DD / 128, MM / 128), dim3(256), 0, stream>>>(QA, Wo, d_out, flag);
}

// Round 7
// 344.111 us; speedup vs baseline: 7.0120x; 1.0735x over previous
//
#include <hip/hip_runtime.h>
#include <hip/hip_bf16.h>
#include <math.h>

// Problem constants (MultiQueryAttention: B=2, S=2048, D=1024, H=16, hd=64)
#define BB 2
#define SS 2048
#define DD 1024
#define NH 16
#define HD 64
#define MM (BB * SS)  // 4096 tokens

typedef __hip_bfloat16 bf16;      // storage type for ws tensors
typedef __bf16 bf16_t;            // native compiler bf16
typedef __attribute__((ext_vector_type(8))) __bf16 bf16x8;
typedef __attribute__((ext_vector_type(4))) __bf16 bf16x4;
typedef __attribute__((ext_vector_type(4))) float floatx4;

// ---------------- runtime dtype detection (parallel) ----------------
// flag==1 -> external tensors are fp32 (the proven world); flag==0 -> bf16.
__global__ void detect_dtype(const unsigned int* __restrict__ x, int* __restrict__ flag) {
    const int tid = threadIdx.x;  // 64 lanes
    int good = 0;
    for (int i = tid; i < 256; i += 64) {
        unsigned int bits = (x[i] & 0xFFFFu) << 16;
        float v = __uint_as_float(bits);
        float av = fabsf(v);
        if (av == 0.f || (av >= 9.5367431640625e-7f && av <= 64.f)) good++;
    }
#pragma unroll
    for (int s = 1; s < 64; s <<= 1) good += __shfl_xor(good, s);
    if (tid == 0) *flag = (good >= 240) ? 0 : 1;
}

// ---------------- MFMA projection GEMMs (round-6, validated) ----------------
// 128x128 tile, BK=32, 4 waves (2x2), 16 mfma_f32_16x16x32_bf16 per K-iter.
#define BK 32
#define KP 40   // LDS row stride in bf16 elems

__global__ __launch_bounds__(256) void proj_qkv(const void* __restrict__ X,
                                                const void* __restrict__ Wq,
                                                const void* __restrict__ Wk,
                                                const void* __restrict__ Wv,
                                                bf16_t* __restrict__ QA,
                                                bf16_t* __restrict__ Kp,
                                                bf16_t* __restrict__ Vp,
                                                const int* __restrict__ flag) {
    const int f = *flag;  // 1 => fp32 inputs

    __shared__ bf16_t As[128 * KP];
    __shared__ bf16_t Ws[128 * KP];

    const int tid = threadIdx.x;
    const int wave = tid >> 6, lane = tid & 63;
    const int lo = lane & 15, quad = lane >> 4;
    const int wr = wave >> 1, wc = wave & 1;
    const int cb = blockIdx.x;              // 0..8 (8 = KV block)
    const int rowBase = blockIdx.y * 128;

    floatx4 acc[4][4];
#pragma unroll
    for (int i = 0; i < 4; i++)
#pragma unroll
        for (int j = 0; j < 4; j++) acc[i][j] = (floatx4){0.f, 0.f, 0.f, 0.f};

    for (int k0 = 0; k0 < DD; k0 += BK) {
        if (f) {
#pragma unroll
            for (int p = 0; p < 4; p++) {
                int chunk = tid + 256 * p;
                int row = chunk >> 3, seg = chunk & 7;
                float4 v = *(const float4*)((const float*)X +
                                            (size_t)(rowBase + row) * DD + k0 + seg * 4);
                bf16x4 o;
                o[0] = (bf16_t)v.x; o[1] = (bf16_t)v.y; o[2] = (bf16_t)v.z; o[3] = (bf16_t)v.w;
                *(bf16x4*)&As[row * KP + seg * 4] = o;
            }
#pragma unroll
            for (int p = 0; p < 4; p++) {
                int chunk = tid + 256 * p;
                int row = chunk >> 3, seg = chunk & 7;
                const float* wsrc;
                if (cb < 8)        wsrc = (const float*)Wq + (size_t)(cb * 128 + row) * DD;
                else if (row < 64) wsrc = (const float*)Wk + (size_t)row * DD;
                else               wsrc = (const float*)Wv + (size_t)(row - 64) * DD;
                float4 v = *(const float4*)(wsrc + k0 + seg * 4);
                bf16x4 o;
                o[0] = (bf16_t)v.x; o[1] = (bf16_t)v.y; o[2] = (bf16_t)v.z; o[3] = (bf16_t)v.w;
                *(bf16x4*)&Ws[row * KP + seg * 4] = o;
            }
        } else {
#pragma unroll
            for (int p = 0; p < 2; p++) {
                int chunk = tid + 256 * p;
                int row = chunk >> 2, seg = chunk & 3;
                *(bf16x8*)&As[row * KP + seg * 8] =
                    *(const bf16x8*)((const bf16_t*)X + (size_t)(rowBase + row) * DD + k0 + seg * 8);
            }
#pragma unroll
            for (int p = 0; p < 2; p++) {
                int chunk = tid + 256 * p;
                int row = chunk >> 2, seg = chunk & 3;
                const bf16_t* wsrc;
                if (cb < 8)        wsrc = (const bf16_t*)Wq + (size_t)(cb * 128 + row) * DD;
                else if (row < 64) wsrc = (const bf16_t*)Wk + (size_t)row * DD;
                else               wsrc = (const bf16_t*)Wv + (size_t)(row - 64) * DD;
                *(bf16x8*)&Ws[row * KP + seg * 8] = *(const bf16x8*)(wsrc + k0 + seg * 8);
            }
        }
        __syncthreads();

        bf16x8 afr[4], bfr[4];
#pragma unroll
        for (int i = 0; i < 4; i++)
            afr[i] = *(const bf16x8*)&As[(wr * 64 + i * 16 + lo) * KP + quad * 8];
#pragma unroll
        for (int j = 0; j < 4; j++)
            bfr[j] = *(const bf16x8*)&Ws[(wc * 64 + j * 16 + lo) * KP + quad * 8];
#pragma unroll
        for (int i = 0; i < 4; i++)
#pragma unroll
            for (int j = 0; j < 4; j++)
                acc[i][j] = __builtin_amdgcn_mfma_f32_16x16x32_bf16(afr[i], bfr[j], acc[i][j], 0, 0, 0);
        __syncthreads();
    }

#pragma unroll
    for (int i = 0; i < 4; i++)
#pragma unroll
        for (int j = 0; j < 4; j++)
#pragma unroll
            for (int reg = 0; reg < 4; reg++) {
                int row = rowBase + wr * 64 + i * 16 + quad * 4 + reg;
                int col = wc * 64 + j * 16 + lo;
                bf16_t val = (bf16_t)acc[i][j][reg];
                if (cb < 8)         QA[(size_t)row * DD + cb * 128 + col] = val;
                else if (col < 64)  Kp[(size_t)row * HD + col] = val;
                else                Vp[(size_t)row * HD + (col - 64)] = val;
            }
}

__global__ __launch_bounds__(256) void proj_o(const bf16_t* __restrict__ AO,
                                              const void* __restrict__ Wo,
                                              void* __restrict__ Cout,
                                              const int* __restrict__ flag) {
    const int f = *flag;

    __shared__ bf16_t As[128 * KP];
    __shared__ bf16_t Ws[128 * KP];

    const int tid = threadIdx.x;
    const int wave = tid >> 6, lane = tid & 63;
    const int lo = lane & 15, quad = lane >> 4;
    const int wr = wave >> 1, wc = wave & 1;
    const int colBase = blockIdx.x * 128;
    const int rowBase = blockIdx.y * 128;

    floatx4 acc[4][4];
#pragma unroll
    for (int i = 0; i < 4; i++)
#pragma unroll
        for (int j = 0; j < 4; j++) acc[i][j] = (floatx4){0.f, 0.f, 0.f, 0.f};

    for (int k0 = 0; k0 < DD; k0 += BK) {
#pragma unroll
        for (int p = 0; p < 2; p++) {
            int chunk = tid + 256 * p;
            int row = chunk >> 2, seg = chunk & 3;
            *(bf16x8*)&As[row * KP + seg * 8] =
                *(const bf16x8*)(AO + (size_t)(rowBase + row) * DD + k0 + seg * 8);
        }
        if (f) {
#pragma unroll
            for (int p = 0; p < 4; p++) {
                int chunk = tid + 256 * p;
                int row = chunk >> 3, seg = chunk & 7;
                float4 v = *(const float4*)((const float*)Wo +
                                            (size_t)(colBase + row) * DD + k0 + seg * 4);
                bf16x4 o;
                o[0] = (bf16_t)v.x; o[1] = (bf16_t)v.y; o[2] = (bf16_t)v.z; o[3] = (bf16_t)v.w;
                *(bf16x4*)&Ws[row * KP + seg * 4] = o;
            }
        } else {
#pragma unroll
            for (int p = 0; p < 2; p++) {
                int chunk = tid + 256 * p;
                int row = chunk >> 2, seg = chunk & 3;
                *(bf16x8*)&Ws[row * KP + seg * 8] =
                    *(const bf16x8*)((const bf16_t*)Wo + (size_t)(colBase + row) * DD + k0 + seg * 8);
            }
        }
        __syncthreads();

        bf16x8 afr[4], bfr[4];
#pragma unroll
        for (int i = 0; i < 4; i++)
            afr[i] = *(const bf16x8*)&As[(wr * 64 + i * 16 + lo) * KP + quad * 8];
#pragma unroll
        for (int j = 0; j < 4; j++)
            bfr[j] = *(const bf16x8*)&Ws[(wc * 64 + j * 16 + lo) * KP + quad * 8];
#pragma unroll
        for (int i = 0; i < 4; i++)
#pragma unroll
            for (int j = 0; j < 4; j++)
                acc[i][j] = __builtin_amdgcn_mfma_f32_16x16x32_bf16(afr[i], bfr[j], acc[i][j], 0, 0, 0);
        __syncthreads();
    }

#pragma unroll
    for (int i = 0; i < 4; i++)
#pragma unroll
        for (int j = 0; j < 4; j++)
#pragma unroll
            for (int reg = 0; reg < 4; reg++) {
                int row = rowBase + wr * 64 + i * 16 + quad * 4 + reg;
                int col = colBase + wc * 64 + j * 16 + lo;
                size_t idx = (size_t)row * DD + col;
                if (f) ((float*)Cout)[idx] = acc[i][j][reg];
                else   ((bf16_t*)Cout)[idx] = (bf16_t)acc[i][j][reg];
            }
}

// ---------------- MFMA flash attention, pipelined ----------------
// Block = 4 waves, 64 q-rows of one (b,h). Register-prefetch of next K/V tile;
// 2 barriers/tile; P LDS round-trip is wave-private (lgkmcnt wait only).
// Heavy q-tiles launch first (qb reversed) for tail packing.
#define LDP 72
#define ALOG2E 0.18033688011112042f   // (1/sqrt(64)) * log2(e)

__global__ __launch_bounds__(256) void attn_mfma(const bf16_t* Q,
                                                 const bf16_t* __restrict__ K,
                                                 const bf16_t* __restrict__ V,
                                                 bf16_t* O) {
    const int qb = (SS / 64 - 1) - blockIdx.x;  // heavy tiles first
    const int h  = blockIdx.y;
    const int b  = blockIdx.z;
    const int q0 = qb * 64;

    const int tid  = threadIdx.x;
    const int wq   = tid >> 6;
    const int lane = tid & 63;
    const int lo   = lane & 15;
    const int quad = lane >> 4;

    __shared__ bf16_t Ks[64 * LDP];
    __shared__ bf16_t Vt[64 * LDP];
    __shared__ bf16_t Ps[4 * 16 * LDP];

    // Q fragments (A operand), loaded once
    const bf16_t* Qrow = Q + ((size_t)(b * SS + q0 + wq * 16 + lo)) * DD + h * HD;
    const bf16x8 qf0 = *(const bf16x8*)(Qrow + quad * 8);
    const bf16x8 qf1 = *(const bf16x8*)(Qrow + 32 + quad * 8);

    floatx4 Oacc[4];
    float m_i[4], l_i[4];
#pragma unroll
    for (int nb = 0; nb < 4; nb++) Oacc[nb] = (floatx4){0.f, 0.f, 0.f, 0.f};
#pragma unroll
    for (int r = 0; r < 4; r++) { m_i[r] = -1e30f; l_i[r] = 0.f; }

    const bf16_t* Kb0 = K + (size_t)(b * SS) * HD;
    const bf16_t* Vb0 = V + (size_t)(b * SS) * HD;
    const int lastTb = q0 >> 6;

    // Per-thread staging slots:
    //   K: chunks tid and tid+256 (key = chunk>>3, seg = chunk&7)
    //   V: dimsegs (tid>>6) and (tid>>6)+4 at key = tid&63
    const int kKey0 = tid >> 3,        kSeg0 = tid & 7;
    const int kKey1 = (tid + 256) >> 3, kSeg1 = tid & 7;
    const int vKey = tid & 63, vDs0 = tid >> 6, vDs1 = (tid >> 6) + 4;

    // Prologue: prefetch tile 0 into registers
    bf16x8 kr0, kr1, vr0, vr1;
    {
        const bf16_t* Kg = Kb0;
        const bf16_t* Vg = Vb0;
        kr0 = *(const bf16x8*)(Kg + kKey0 * HD + kSeg0 * 8);
        kr1 = *(const bf16x8*)(Kg + kKey1 * HD + kSeg1 * 8);
        vr0 = *(const bf16x8*)(Vg + vKey * HD + vDs0 * 8);
        vr1 = *(const bf16x8*)(Vg + vKey * HD + vDs1 * 8);
    }

    for (int tb = 0; tb <= lastTb; tb++) {
        __syncthreads();  // all waves done reading LDS tile tb-1

        // ---- store prefetched tile tb to LDS ----
        *(bf16x8*)&Ks[kKey0 * LDP + kSeg0 * 8] = kr0;
        *(bf16x8*)&Ks[kKey1 * LDP + kSeg1 * 8] = kr1;
#pragma unroll
        for (int j = 0; j < 8; j++) Vt[(vDs0 * 8 + j) * LDP + vKey] = vr0[j];
#pragma unroll
        for (int j = 0; j < 8; j++) Vt[(vDs1 * 8 + j) * LDP + vKey] = vr1[j];
        __syncthreads();  // tile tb visible

        // ---- issue prefetch of tile tb+1 (latency overlaps compute) ----
        if (tb < lastTb) {
            const bf16_t* Kg = Kb0 + (size_t)(tb + 1) * 64 * HD;
            const bf16_t* Vg = Vb0 + (size_t)(tb + 1) * 64 * HD;
            kr0 = *(const bf16x8*)(Kg + kKey0 * HD + kSeg0 * 8);
            kr1 = *(const bf16x8*)(Kg + kKey1 * HD + kSeg1 * 8);
            vr0 = *(const bf16x8*)(Vg + vKey * HD + vDs0 * 8);
            vr1 = *(const bf16x8*)(Vg + vKey * HD + vDs1 * 8);
        }

        // ---- QK^T ----
        floatx4 sc[4];
#pragma unroll
        for (int nb = 0; nb < 4; nb++) {
            const bf16x8 kf0 = *(const bf16x8*)&Ks[(nb * 16 + lo) * LDP + quad * 8];
            const bf16x8 kf1 = *(const bf16x8*)&Ks[(nb * 16 + lo) * LDP + 32 + quad * 8];
            floatx4 z = (floatx4){0.f, 0.f, 0.f, 0.f};
            z = __builtin_amdgcn_mfma_f32_16x16x32_bf16(qf0, kf0, z, 0, 0, 0);
            z = __builtin_amdgcn_mfma_f32_16x16x32_bf16(qf1, kf1, z, 0, 0, 0);
            sc[nb] = z;
        }

        // ---- causal mask (diagonal tile only) ----
        if (tb == lastTb) {
            const int rowg = q0 + wq * 16 + quad * 4;
            const int keyg = tb * 64 + lo;
#pragma unroll
            for (int nb = 0; nb < 4; nb++)
#pragma unroll
                for (int reg = 0; reg < 4; reg++)
                    if (keyg + nb * 16 > rowg + reg) sc[nb][reg] = -1e30f;
        }

        // ---- online softmax ----
        float al[4], rs[4];
#pragma unroll
        for (int reg = 0; reg < 4; reg++) {
            float v = fmaxf(fmaxf(sc[0][reg], sc[1][reg]), fmaxf(sc[2][reg], sc[3][reg]));
#pragma unroll
            for (int s = 1; s < 16; s <<= 1) v = fmaxf(v, __shfl_xor(v, s));
            float mn = fmaxf(m_i[reg], v);
            al[reg] = exp2f((m_i[reg] - mn) * ALOG2E);
            m_i[reg] = mn;
            rs[reg] = 0.f;
        }
        bf16_t* Pw = &Ps[wq * 16 * LDP];
#pragma unroll
        for (int nb = 0; nb < 4; nb++)
#pragma unroll
            for (int reg = 0; reg < 4; reg++) {
                float p = exp2f((sc[nb][reg] - m_i[reg]) * ALOG2E);
                rs[reg] += p;
                Pw[(quad * 4 + reg) * LDP + nb * 16 + lo] = (bf16_t)p;
            }
#pragma unroll
        for (int reg = 0; reg < 4; reg++) {
            float v = rs[reg];
#pragma unroll
            for (int s = 1; s < 16; s <<= 1) v += __shfl_xor(v, s);
            l_i[reg] = l_i[reg] * al[reg] + v;
#pragma unroll
            for (int nb = 0; nb < 4; nb++) Oacc[nb][reg] *= al[reg];
        }

        // Ps is wave-private: only need LDS writes drained, not a barrier.
        asm volatile("s_waitcnt lgkmcnt(0)" ::: "memory");

        // ---- P @ V ----
        const bf16x8 af0 = *(const bf16x8*)&Pw[lo * LDP + quad * 8];
        const bf16x8 af1 = *(const bf16x8*)&Pw[lo * LDP + 32 + quad * 8];
#pragma unroll
        for (int nb = 0; nb < 4; nb++) {
            const bf16x8 vf0 = *(const bf16x8*)&Vt[(nb * 16 + lo) * LDP + quad * 8];
            const bf16x8 vf1 = *(const bf16x8*)&Vt[(nb * 16 + lo) * LDP + 32 + quad * 8];
            Oacc[nb] = __builtin_amdgcn_mfma_f32_16x16x32_bf16(af0, vf0, Oacc[nb], 0, 0, 0);
            Oacc[nb] = __builtin_amdgcn_mfma_f32_16x16x32_bf16(af1, vf1, Oacc[nb], 0, 0, 0);
        }
    }

#pragma unroll
    for (int reg = 0; reg < 4; reg++) {
        float inv = 1.f / l_i[reg];
        bf16_t* Orow = O + ((size_t)(b * SS + q0 + wq * 16 + quad * 4 + reg)) * DD + h * HD;
#pragma unroll
        for (int nb = 0; nb < 4; nb++)
            Orow[nb * 16 + lo] = (bf16_t)(Oacc[nb][reg] * inv);
    }
}

// ---------------- launch ----------------
extern "C" void kernel_launch(void* const* d_in, const int* in_sizes, int n_in,
                              void* d_out, int out_size, void* d_ws, size_t ws_size,
                              hipStream_t stream) {
    const void* x  = d_in[0];
    const void* Wq = d_in[1];
    const void* Wk = d_in[2];
    const void* Wv = d_in[3];
    const void* Wo = d_in[4];
    // d_in[5] = causal mask — known tril, handled analytically in attn_mfma.

    // Workspace (~9.0 MB): [flag 256B] | QA bf16[4096,1024] (Q -> attention
    // output in-place) | K bf16[4096,64] | V bf16[4096,64]
    char* ws = (char*)d_ws;
    int* flag = (int*)ws;
    bf16_t* QA = (bf16_t*)(ws + 256);
    bf16_t* Kp = QA + (size_t)MM * DD;
    bf16_t* Vp = Kp + (size_t)MM * HD;

    detect_dtype<<<1, 64, 0, stream>>>((const unsigned int*)x, flag);

    proj_qkv<<<dim3(9, MM / 128), dim3(256), 0, stream>>>(x, Wq, Wk, Wv, QA, Kp, Vp, flag);

    attn_mfma<<<dim3(SS / 64, NH, BB), dim3(256), 0, stream>>>(QA, Kp, Vp, QA);

    proj_o<<<dim3(DD / 128, MM / 128), dim3(256), 0, stream>>>(QA, Wo, d_out, flag);
}

// Round 8
// 331.917 us; speedup vs baseline: 7.2696x; 1.0367x over previous
//
#include <hip/hip_runtime.h>
#include <hip/hip_bf16.h>
#include <math.h>

// Problem constants (MultiQueryAttention: B=2, S=2048, D=1024, H=16, hd=64)
#define BB 2
#define SS 2048
#define DD 1024
#define NH 16
#define HD 64
#define MM (BB * SS)  // 4096 tokens

typedef __hip_bfloat16 bf16;      // storage type for ws tensors
typedef __bf16 bf16_t;            // native compiler bf16
typedef __attribute__((ext_vector_type(8))) __bf16 bf16x8;
typedef __attribute__((ext_vector_type(4))) __bf16 bf16x4;
typedef __attribute__((ext_vector_type(4))) float floatx4;

// ---------------- runtime dtype detection (parallel) ----------------
// flag==1 -> external tensors are fp32 (the proven world); flag==0 -> bf16.
__global__ void detect_dtype(const unsigned int* __restrict__ x, int* __restrict__ flag) {
    const int tid = threadIdx.x;  // 64 lanes
    int good = 0;
    for (int i = tid; i < 256; i += 64) {
        unsigned int bits = (x[i] & 0xFFFFu) << 16;
        float v = __uint_as_float(bits);
        float av = fabsf(v);
        if (av == 0.f || (av >= 9.5367431640625e-7f && av <= 64.f)) good++;
    }
#pragma unroll
    for (int s = 1; s < 64; s <<= 1) good += __shfl_xor(good, s);
    if (tid == 0) *flag = (good >= 240) ? 0 : 1;
}

// ---------------- MFMA projection GEMMs ----------------
// 128x128 tile, BK=32, 4 waves (2x2), 16 mfma_f32_16x16x32_bf16 per K-iter.
#define BK 32
#define KP 40   // LDS row stride in bf16 elems

// Fused QKV projection. Q -> QA [token][1024]; K -> Kp [token][64];
// V -> VpT [b][dim][token] (transposed, for barrier-free PV B-frags).
__global__ __launch_bounds__(256) void proj_qkv(const void* __restrict__ X,
                                                const void* __restrict__ Wq,
                                                const void* __restrict__ Wk,
                                                const void* __restrict__ Wv,
                                                bf16_t* __restrict__ QA,
                                                bf16_t* __restrict__ Kp,
                                                bf16_t* __restrict__ VpT,
                                                const int* __restrict__ flag) {
    const int f = *flag;  // 1 => fp32 inputs

    __shared__ bf16_t As[128 * KP];
    __shared__ bf16_t Ws[128 * KP];

    const int tid = threadIdx.x;
    const int wave = tid >> 6, lane = tid & 63;
    const int lo = lane & 15, quad = lane >> 4;
    const int wr = wave >> 1, wc = wave & 1;
    const int cb = blockIdx.x;              // 0..8 (8 = KV block)
    const int rowBase = blockIdx.y * 128;

    floatx4 acc[4][4];
#pragma unroll
    for (int i = 0; i < 4; i++)
#pragma unroll
        for (int j = 0; j < 4; j++) acc[i][j] = (floatx4){0.f, 0.f, 0.f, 0.f};

    for (int k0 = 0; k0 < DD; k0 += BK) {
        if (f) {
#pragma unroll
            for (int p = 0; p < 4; p++) {
                int chunk = tid + 256 * p;
                int row = chunk >> 3, seg = chunk & 7;
                float4 v = *(const float4*)((const float*)X +
                                            (size_t)(rowBase + row) * DD + k0 + seg * 4);
                bf16x4 o;
                o[0] = (bf16_t)v.x; o[1] = (bf16_t)v.y; o[2] = (bf16_t)v.z; o[3] = (bf16_t)v.w;
                *(bf16x4*)&As[row * KP + seg * 4] = o;
            }
#pragma unroll
            for (int p = 0; p < 4; p++) {
                int chunk = tid + 256 * p;
                int row = chunk >> 3, seg = chunk & 7;
                const float* wsrc;
                if (cb < 8)        wsrc = (const float*)Wq + (size_t)(cb * 128 + row) * DD;
                else if (row < 64) wsrc = (const float*)Wk + (size_t)row * DD;
                else               wsrc = (const float*)Wv + (size_t)(row - 64) * DD;
                float4 v = *(const float4*)(wsrc + k0 + seg * 4);
                bf16x4 o;
                o[0] = (bf16_t)v.x; o[1] = (bf16_t)v.y; o[2] = (bf16_t)v.z; o[3] = (bf16_t)v.w;
                *(bf16x4*)&Ws[row * KP + seg * 4] = o;
            }
        } else {
#pragma unroll
            for (int p = 0; p < 2; p++) {
                int chunk = tid + 256 * p;
                int row = chunk >> 2, seg = chunk & 3;
                *(bf16x8*)&As[row * KP + seg * 8] =
                    *(const bf16x8*)((const bf16_t*)X + (size_t)(rowBase + row) * DD + k0 + seg * 8);
            }
#pragma unroll
            for (int p = 0; p < 2; p++) {
                int chunk = tid + 256 * p;
                int row = chunk >> 2, seg = chunk & 3;
                const bf16_t* wsrc;
                if (cb < 8)        wsrc = (const bf16_t*)Wq + (size_t)(cb * 128 + row) * DD;
                else if (row < 64) wsrc = (const bf16_t*)Wk + (size_t)row * DD;
                else               wsrc = (const bf16_t*)Wv + (size_t)(row - 64) * DD;
                *(bf16x8*)&Ws[row * KP + seg * 8] = *(const bf16x8*)(wsrc + k0 + seg * 8);
            }
        }
        __syncthreads();

        bf16x8 afr[4], bfr[4];
#pragma unroll
        for (int i = 0; i < 4; i++)
            afr[i] = *(const bf16x8*)&As[(wr * 64 + i * 16 + lo) * KP + quad * 8];
#pragma unroll
        for (int j = 0; j < 4; j++)
            bfr[j] = *(const bf16x8*)&Ws[(wc * 64 + j * 16 + lo) * KP + quad * 8];
#pragma unroll
        for (int i = 0; i < 4; i++)
#pragma unroll
            for (int j = 0; j < 4; j++)
                acc[i][j] = __builtin_amdgcn_mfma_f32_16x16x32_bf16(afr[i], bfr[j], acc[i][j], 0, 0, 0);
        __syncthreads();
    }

#pragma unroll
    for (int i = 0; i < 4; i++)
#pragma unroll
        for (int j = 0; j < 4; j++)
#pragma unroll
            for (int reg = 0; reg < 4; reg++) {
                int row = rowBase + wr * 64 + i * 16 + quad * 4 + reg;  // token
                int col = wc * 64 + j * 16 + lo;
                bf16_t val = (bf16_t)acc[i][j][reg];
                if (cb < 8)         QA[(size_t)row * DD + cb * 128 + col] = val;
                else if (col < 64)  Kp[(size_t)row * HD + col] = val;
                else {
                    int d = col - 64;
                    VpT[((size_t)(row >> 11) * HD + d) * SS + (row & (SS - 1))] = val;
                }
            }
}

__global__ __launch_bounds__(256) void proj_o(const bf16_t* __restrict__ AO,
                                              const void* __restrict__ Wo,
                                              void* __restrict__ Cout,
                                              const int* __restrict__ flag) {
    const int f = *flag;

    __shared__ bf16_t As[128 * KP];
    __shared__ bf16_t Ws[128 * KP];

    const int tid = threadIdx.x;
    const int wave = tid >> 6, lane = tid & 63;
    const int lo = lane & 15, quad = lane >> 4;
    const int wr = wave >> 1, wc = wave & 1;
    const int colBase = blockIdx.x * 128;
    const int rowBase = blockIdx.y * 128;

    floatx4 acc[4][4];
#pragma unroll
    for (int i = 0; i < 4; i++)
#pragma unroll
        for (int j = 0; j < 4; j++) acc[i][j] = (floatx4){0.f, 0.f, 0.f, 0.f};

    for (int k0 = 0; k0 < DD; k0 += BK) {
#pragma unroll
        for (int p = 0; p < 2; p++) {
            int chunk = tid + 256 * p;
            int row = chunk >> 2, seg = chunk & 3;
            *(bf16x8*)&As[row * KP + seg * 8] =
                *(const bf16x8*)(AO + (size_t)(rowBase + row) * DD + k0 + seg * 8);
        }
        if (f) {
#pragma unroll
            for (int p = 0; p < 4; p++) {
                int chunk = tid + 256 * p;
                int row = chunk >> 3, seg = chunk & 7;
                float4 v = *(const float4*)((const float*)Wo +
                                            (size_t)(colBase + row) * DD + k0 + seg * 4);
                bf16x4 o;
                o[0] = (bf16_t)v.x; o[1] = (bf16_t)v.y; o[2] = (bf16_t)v.z; o[3] = (bf16_t)v.w;
                *(bf16x4*)&Ws[row * KP + seg * 4] = o;
            }
        } else {
#pragma unroll
            for (int p = 0; p < 2; p++) {
                int chunk = tid + 256 * p;
                int row = chunk >> 2, seg = chunk & 3;
                *(bf16x8*)&Ws[row * KP + seg * 8] =
                    *(const bf16x8*)((const bf16_t*)Wo + (size_t)(colBase + row) * DD + k0 + seg * 8);
            }
        }
        __syncthreads();

        bf16x8 afr[4], bfr[4];
#pragma unroll
        for (int i = 0; i < 4; i++)
            afr[i] = *(const bf16x8*)&As[(wr * 64 + i * 16 + lo) * KP + quad * 8];
#pragma unroll
        for (int j = 0; j < 4; j++)
            bfr[j] = *(const bf16x8*)&Ws[(wc * 64 + j * 16 + lo) * KP + quad * 8];
#pragma unroll
        for (int i = 0; i < 4; i++)
#pragma unroll
            for (int j = 0; j < 4; j++)
                acc[i][j] = __builtin_amdgcn_mfma_f32_16x16x32_bf16(afr[i], bfr[j], acc[i][j], 0, 0, 0);
        __syncthreads();
    }

#pragma unroll
    for (int i = 0; i < 4; i++)
#pragma unroll
        for (int j = 0; j < 4; j++)
#pragma unroll
            for (int reg = 0; reg < 4; reg++) {
                int row = rowBase + wr * 64 + i * 16 + quad * 4 + reg;
                int col = colBase + wc * 64 + j * 16 + lo;
                size_t idx = (size_t)row * DD + col;
                if (f) ((float*)Cout)[idx] = acc[i][j][reg];
                else   ((bf16_t*)Cout)[idx] = (bf16_t)acc[i][j][reg];
            }
}

// ---------------- barrier-free MFMA flash attention ----------------
// One WAVE = one independent task: 32 query rows of one (b,h), looping 32-key
// tiles with online softmax. K/V read directly from global (L2-resident:
// 256 KB per batch). No __syncthreads anywhere in the loop; P round-trips
// through wave-private LDS with lgkmcnt-only waits. K regs double-buffered;
// V loads issued a softmax ahead of use. Heavy tasks launch first.
#define PSTR 40   // P row stride in bf16 (80 B = 5x16 B, 16B-aligned)
#define ALOG2E 0.18033688011112042f   // (1/sqrt(64)) * log2(e)

__global__ __launch_bounds__(256) void attn_mfma(const bf16_t* Q,
                                                 const bf16_t* __restrict__ K,
                                                 const bf16_t* __restrict__ Vt,
                                                 bf16_t* O) {
    const int h = blockIdx.y, b = blockIdx.z;
    const int tid = threadIdx.x;
    const int wq = tid >> 6, lane = tid & 63;
    const int lo = lane & 15, quad = lane >> 4;
    const int qt = (SS / 32 - 1) - (blockIdx.x * 4 + wq);  // heavy first
    const int q0 = qt * 32;

    __shared__ bf16_t Ps[4][32 * PSTR];
    bf16_t* Pw = Ps[wq];

    // Q A-frags: [sub-tile s][dim-half]
    bf16x8 qf[2][2];
#pragma unroll
    for (int s = 0; s < 2; s++)
#pragma unroll
        for (int hf = 0; hf < 2; hf++)
            qf[s][hf] = *(const bf16x8*)(Q + ((size_t)(b * SS + q0 + s * 16 + lo)) * DD +
                                         h * HD + hf * 32 + quad * 8);

    floatx4 Oacc[2][4];
    float m_i[2][4], l_i[2][4];
#pragma unroll
    for (int s = 0; s < 2; s++) {
#pragma unroll
        for (int dt = 0; dt < 4; dt++) Oacc[s][dt] = (floatx4){0.f, 0.f, 0.f, 0.f};
#pragma unroll
        for (int r = 0; r < 4; r++) { m_i[s][r] = -1e30f; l_i[s][r] = 0.f; }
    }

    const bf16_t* Kb = K + (size_t)b * SS * HD;
    const bf16_t* Vb = Vt + (size_t)b * HD * SS;

    // preload K tile 0: [key-subtile kt][dim-half]
    bf16x8 kf[2][2];
#pragma unroll
    for (int kt = 0; kt < 2; kt++)
#pragma unroll
        for (int hf = 0; hf < 2; hf++)
            kf[kt][hf] = *(const bf16x8*)(Kb + (size_t)(kt * 16 + lo) * HD + hf * 32 + quad * 8);

    for (int it = 0; it <= qt; it++) {
        const int t0 = it * 32;

        // V loads for this iter (consumed after softmax — latency hidden)
        bf16x8 vf[4];
#pragma unroll
        for (int dt = 0; dt < 4; dt++)
            vf[dt] = *(const bf16x8*)(Vb + (size_t)(dt * 16 + lo) * SS + t0 + quad * 8);

        // K prefetch for next iter
        bf16x8 kn[2][2];
        if (it < qt) {
#pragma unroll
            for (int kt = 0; kt < 2; kt++)
#pragma unroll
                for (int hf = 0; hf < 2; hf++)
                    kn[kt][hf] = *(const bf16x8*)(Kb + (size_t)(t0 + 32 + kt * 16 + lo) * HD +
                                                  hf * 32 + quad * 8);
        }

        // ---- QK^T: sc[s][kt], q-row = quad*4+reg, key-col = lo ----
        floatx4 sc[2][2];
#pragma unroll
        for (int s = 0; s < 2; s++)
#pragma unroll
            for (int kt = 0; kt < 2; kt++) {
                floatx4 z = (floatx4){0.f, 0.f, 0.f, 0.f};
                z = __builtin_amdgcn_mfma_f32_16x16x32_bf16(qf[s][0], kf[kt][0], z, 0, 0, 0);
                z = __builtin_amdgcn_mfma_f32_16x16x32_bf16(qf[s][1], kf[kt][1], z, 0, 0, 0);
                sc[s][kt] = z;
            }

        // ---- causal mask (diagonal iter only) ----
        if (it == qt) {
#pragma unroll
            for (int s = 0; s < 2; s++)
#pragma unroll
                for (int kt = 0; kt < 2; kt++) {
                    int t = t0 + kt * 16 + lo;
#pragma unroll
                    for (int reg = 0; reg < 4; reg++)
                        if (t > q0 + s * 16 + quad * 4 + reg) sc[s][kt][reg] = -1e30f;
                }
        }

        // ---- online softmax (per q-row; reductions within 16-lane groups) ----
#pragma unroll
        for (int s = 0; s < 2; s++)
#pragma unroll
            for (int reg = 0; reg < 4; reg++) {
                float v = fmaxf(sc[s][0][reg], sc[s][1][reg]);
#pragma unroll
                for (int sh = 1; sh < 16; sh <<= 1) v = fmaxf(v, __shfl_xor(v, sh));
                float mn = fmaxf(m_i[s][reg], v);
                float al = exp2f((m_i[s][reg] - mn) * ALOG2E);
                m_i[s][reg] = mn;
                float p0 = exp2f((sc[s][0][reg] - mn) * ALOG2E);
                float p1 = exp2f((sc[s][1][reg] - mn) * ALOG2E);
                float rs = p0 + p1;
#pragma unroll
                for (int sh = 1; sh < 16; sh <<= 1) rs += __shfl_xor(rs, sh);
                l_i[s][reg] = l_i[s][reg] * al + rs;
                int prow = (s * 16 + quad * 4 + reg) * PSTR;
                Pw[prow + lo] = (bf16_t)p0;
                Pw[prow + 16 + lo] = (bf16_t)p1;
#pragma unroll
                for (int dt = 0; dt < 4; dt++) Oacc[s][dt][reg] *= al;
            }

        // wave-private LDS: drain writes, no barrier
        asm volatile("s_waitcnt lgkmcnt(0)" ::: "memory");

        // ---- P @ V ----
        bf16x8 pa[2];
#pragma unroll
        for (int s = 0; s < 2; s++)
            pa[s] = *(const bf16x8*)&Pw[(s * 16 + lo) * PSTR + quad * 8];
#pragma unroll
        for (int s = 0; s < 2; s++)
#pragma unroll
            for (int dt = 0; dt < 4; dt++)
                Oacc[s][dt] = __builtin_amdgcn_mfma_f32_16x16x32_bf16(pa[s], vf[dt], Oacc[s][dt], 0, 0, 0);

        // rotate K double-buffer
#pragma unroll
        for (int kt = 0; kt < 2; kt++)
#pragma unroll
            for (int hf = 0; hf < 2; hf++) kf[kt][hf] = kn[kt][hf];
    }

    // ---- epilogue: normalize, write in-place over own Q region ----
#pragma unroll
    for (int s = 0; s < 2; s++)
#pragma unroll
        for (int reg = 0; reg < 4; reg++) {
            float inv = 1.f / l_i[s][reg];
            bf16_t* Orow = O + ((size_t)(b * SS + q0 + s * 16 + quad * 4 + reg)) * DD + h * HD;
#pragma unroll
            for (int dt = 0; dt < 4; dt++)
                Orow[dt * 16 + lo] = (bf16_t)(Oacc[s][dt][reg] * inv);
        }
}

// ---------------- launch ----------------
extern "C" void kernel_launch(void* const* d_in, const int* in_sizes, int n_in,
                              void* d_out, int out_size, void* d_ws, size_t ws_size,
                              hipStream_t stream) {
    const void* x  = d_in[0];
    const void* Wq = d_in[1];
    const void* Wk = d_in[2];
    const void* Wv = d_in[3];
    const void* Wo = d_in[4];
    // d_in[5] = causal mask — known tril, handled analytically in attn_mfma.

    // Workspace (~9.0 MB): [flag 256B] | QA bf16[4096,1024] (Q -> attention
    // output in-place) | Kp bf16[4096,64] | VpT bf16[2][64][2048]
    char* ws = (char*)d_ws;
    int* flag = (int*)ws;
    bf16_t* QA  = (bf16_t*)(ws + 256);
    bf16_t* Kp  = QA + (size_t)MM * DD;
    bf16_t* VpT = Kp + (size_t)MM * HD;

    detect_dtype<<<1, 64, 0, stream>>>((const unsigned int*)x, flag);

    proj_qkv<<<dim3(9, MM / 128), dim3(256), 0, stream>>>(x, Wq, Wk, Wv, QA, Kp, VpT, flag);

    // Barrier-free attention: 64 wave-tasks/(b,h) in 16 blocks of 4 waves
    attn_mfma<<<dim3(SS / 32 / 4, NH, BB), dim3(256), 0, stream>>>(QA, Kp, VpT, QA);

    proj_o<<<dim3(DD / 128, MM / 128), dim3(256), 0, stream>>>(QA, Wo, d_out, flag);
}

// Round 9
// 294.470 us; speedup vs baseline: 8.1941x; 1.1272x over previous
//
#include <hip/hip_runtime.h>
#include <hip/hip_bf16.h>
#include <math.h>

// Problem constants (MultiQueryAttention: B=2, S=2048, D=1024, H=16, hd=64)
#define BB 2
#define SS 2048
#define DD 1024
#define NH 16
#define HD 64
#define MM (BB * SS)  // 4096 tokens

typedef __hip_bfloat16 bf16;      // storage type for ws tensors
typedef __bf16 bf16_t;            // native compiler bf16
typedef __attribute__((ext_vector_type(8))) __bf16 bf16x8;
typedef __attribute__((ext_vector_type(4))) __bf16 bf16x4;
typedef __attribute__((ext_vector_type(4))) float floatx4;

// ---------------- runtime dtype detection (parallel) ----------------
// flag==1 -> external tensors are fp32 (the proven world); flag==0 -> bf16.
__global__ void detect_dtype(const unsigned int* __restrict__ x, int* __restrict__ flag) {
    const int tid = threadIdx.x;  // 64 lanes
    int good = 0;
    for (int i = tid; i < 256; i += 64) {
        unsigned int bits = (x[i] & 0xFFFFu) << 16;
        float v = __uint_as_float(bits);
        float av = fabsf(v);
        if (av == 0.f || (av >= 9.5367431640625e-7f && av <= 64.f)) good++;
    }
#pragma unroll
    for (int s = 1; s < 64; s <<= 1) good += __shfl_xor(good, s);
    if (tid == 0) *flag = (good >= 240) ? 0 : 1;
}

// ---------------- MFMA projection GEMMs ----------------
// 128x128 tile, BK=32, 4 waves (2x2), 16 mfma_f32_16x16x32_bf16 per K-iter.
#define BK 32
#define KP 40   // LDS row stride in bf16 elems

// Fused QKV projection. Q -> QA [token][1024]; K -> Kp [token][64];
// V -> VpT [b][dim][token] (transposed, for barrier-free PV A-frags).
__global__ __launch_bounds__(256) void proj_qkv(const void* __restrict__ X,
                                                const void* __restrict__ Wq,
                                                const void* __restrict__ Wk,
                                                const void* __restrict__ Wv,
                                                bf16_t* __restrict__ QA,
                                                bf16_t* __restrict__ Kp,
                                                bf16_t* __restrict__ VpT,
                                                const int* __restrict__ flag) {
    const int f = *flag;  // 1 => fp32 inputs

    __shared__ bf16_t As[128 * KP];
    __shared__ bf16_t Ws[128 * KP];

    const int tid = threadIdx.x;
    const int wave = tid >> 6, lane = tid & 63;
    const int lo = lane & 15, quad = lane >> 4;
    const int wr = wave >> 1, wc = wave & 1;
    const int cb = blockIdx.x;              // 0..8 (8 = KV block)
    const int rowBase = blockIdx.y * 128;

    floatx4 acc[4][4];
#pragma unroll
    for (int i = 0; i < 4; i++)
#pragma unroll
        for (int j = 0; j < 4; j++) acc[i][j] = (floatx4){0.f, 0.f, 0.f, 0.f};

    for (int k0 = 0; k0 < DD; k0 += BK) {
        if (f) {
#pragma unroll
            for (int p = 0; p < 4; p++) {
                int chunk = tid + 256 * p;
                int row = chunk >> 3, seg = chunk & 7;
                float4 v = *(const float4*)((const float*)X +
                                            (size_t)(rowBase + row) * DD + k0 + seg * 4);
                bf16x4 o;
                o[0] = (bf16_t)v.x; o[1] = (bf16_t)v.y; o[2] = (bf16_t)v.z; o[3] = (bf16_t)v.w;
                *(bf16x4*)&As[row * KP + seg * 4] = o;
            }
#pragma unroll
            for (int p = 0; p < 4; p++) {
                int chunk = tid + 256 * p;
                int row = chunk >> 3, seg = chunk & 7;
                const float* wsrc;
                if (cb < 8)        wsrc = (const float*)Wq + (size_t)(cb * 128 + row) * DD;
                else if (row < 64) wsrc = (const float*)Wk + (size_t)row * DD;
                else               wsrc = (const float*)Wv + (size_t)(row - 64) * DD;
                float4 v = *(const float4*)(wsrc + k0 + seg * 4);
                bf16x4 o;
                o[0] = (bf16_t)v.x; o[1] = (bf16_t)v.y; o[2] = (bf16_t)v.z; o[3] = (bf16_t)v.w;
                *(bf16x4*)&Ws[row * KP + seg * 4] = o;
            }
        } else {
#pragma unroll
            for (int p = 0; p < 2; p++) {
                int chunk = tid + 256 * p;
                int row = chunk >> 2, seg = chunk & 3;
                *(bf16x8*)&As[row * KP + seg * 8] =
                    *(const bf16x8*)((const bf16_t*)X + (size_t)(rowBase + row) * DD + k0 + seg * 8);
            }
#pragma unroll
            for (int p = 0; p < 2; p++) {
                int chunk = tid + 256 * p;
                int row = chunk >> 2, seg = chunk & 3;
                const bf16_t* wsrc;
                if (cb < 8)        wsrc = (const bf16_t*)Wq + (size_t)(cb * 128 + row) * DD;
                else if (row < 64) wsrc = (const bf16_t*)Wk + (size_t)row * DD;
                else               wsrc = (const bf16_t*)Wv + (size_t)(row - 64) * DD;
                *(bf16x8*)&Ws[row * KP + seg * 8] = *(const bf16x8*)(wsrc + k0 + seg * 8);
            }
        }
        __syncthreads();

        bf16x8 afr[4], bfr[4];
#pragma unroll
        for (int i = 0; i < 4; i++)
            afr[i] = *(const bf16x8*)&As[(wr * 64 + i * 16 + lo) * KP + quad * 8];
#pragma unroll
        for (int j = 0; j < 4; j++)
            bfr[j] = *(const bf16x8*)&Ws[(wc * 64 + j * 16 + lo) * KP + quad * 8];
#pragma unroll
        for (int i = 0; i < 4; i++)
#pragma unroll
            for (int j = 0; j < 4; j++)
                acc[i][j] = __builtin_amdgcn_mfma_f32_16x16x32_bf16(afr[i], bfr[j], acc[i][j], 0, 0, 0);
        __syncthreads();
    }

#pragma unroll
    for (int i = 0; i < 4; i++)
#pragma unroll
        for (int j = 0; j < 4; j++)
#pragma unroll
            for (int reg = 0; reg < 4; reg++) {
                int row = rowBase + wr * 64 + i * 16 + quad * 4 + reg;  // token
                int col = wc * 64 + j * 16 + lo;
                bf16_t val = (bf16_t)acc[i][j][reg];
                if (cb < 8)         QA[(size_t)row * DD + cb * 128 + col] = val;
                else if (col < 64)  Kp[(size_t)row * HD + col] = val;
                else {
                    int d = col - 64;
                    VpT[((size_t)(row >> 11) * HD + d) * SS + (row & (SS - 1))] = val;
                }
            }
}

__global__ __launch_bounds__(256) void proj_o(const bf16_t* __restrict__ AO,
                                              const void* __restrict__ Wo,
                                              void* __restrict__ Cout,
                                              const int* __restrict__ flag) {
    const int f = *flag;

    __shared__ bf16_t As[128 * KP];
    __shared__ bf16_t Ws[128 * KP];

    const int tid = threadIdx.x;
    const int wave = tid >> 6, lane = tid & 63;
    const int lo = lane & 15, quad = lane >> 4;
    const int wr = wave >> 1, wc = wave & 1;
    const int colBase = blockIdx.x * 128;
    const int rowBase = blockIdx.y * 128;

    floatx4 acc[4][4];
#pragma unroll
    for (int i = 0; i < 4; i++)
#pragma unroll
        for (int j = 0; j < 4; j++) acc[i][j] = (floatx4){0.f, 0.f, 0.f, 0.f};

    for (int k0 = 0; k0 < DD; k0 += BK) {
#pragma unroll
        for (int p = 0; p < 2; p++) {
            int chunk = tid + 256 * p;
            int row = chunk >> 2, seg = chunk & 3;
            *(bf16x8*)&As[row * KP + seg * 8] =
                *(const bf16x8*)(AO + (size_t)(rowBase + row) * DD + k0 + seg * 8);
        }
        if (f) {
#pragma unroll
            for (int p = 0; p < 4; p++) {
                int chunk = tid + 256 * p;
                int row = chunk >> 3, seg = chunk & 7;
                float4 v = *(const float4*)((const float*)Wo +
                                            (size_t)(colBase + row) * DD + k0 + seg * 4);
                bf16x4 o;
                o[0] = (bf16_t)v.x; o[1] = (bf16_t)v.y; o[2] = (bf16_t)v.z; o[3] = (bf16_t)v.w;
                *(bf16x4*)&Ws[row * KP + seg * 4] = o;
            }
        } else {
#pragma unroll
            for (int p = 0; p < 2; p++) {
                int chunk = tid + 256 * p;
                int row = chunk >> 2, seg = chunk & 3;
                *(bf16x8*)&Ws[row * KP + seg * 8] =
                    *(const bf16x8*)((const bf16_t*)Wo + (size_t)(colBase + row) * DD + k0 + seg * 8);
            }
        }
        __syncthreads();

        bf16x8 afr[4], bfr[4];
#pragma unroll
        for (int i = 0; i < 4; i++)
            afr[i] = *(const bf16x8*)&As[(wr * 64 + i * 16 + lo) * KP + quad * 8];
#pragma unroll
        for (int j = 0; j < 4; j++)
            bfr[j] = *(const bf16x8*)&Ws[(wc * 64 + j * 16 + lo) * KP + quad * 8];
#pragma unroll
        for (int i = 0; i < 4; i++)
#pragma unroll
            for (int j = 0; j < 4; j++)
                acc[i][j] = __builtin_amdgcn_mfma_f32_16x16x32_bf16(afr[i], bfr[j], acc[i][j], 0, 0, 0);
        __syncthreads();
    }

#pragma unroll
    for (int i = 0; i < 4; i++)
#pragma unroll
        for (int j = 0; j < 4; j++)
#pragma unroll
            for (int reg = 0; reg < 4; reg++) {
                int row = rowBase + wr * 64 + i * 16 + quad * 4 + reg;
                int col = colBase + wc * 64 + j * 16 + lo;
                size_t idx = (size_t)row * DD + col;
                if (f) ((float*)Cout)[idx] = acc[i][j][reg];
                else   ((bf16_t*)Cout)[idx] = (bf16_t)acc[i][j][reg];
            }
}

// ---------------- barrier-free MFMA flash attention, transposed scores ----------------
// One WAVE = one task: 32 q-rows of one (b,h). Scores computed TRANSPOSED
// (S^T = K·Q^T) so each lane owns one q-row: softmax max/sum are in-register
// (+2 shuffles), killing the R8 dependent-shuffle chain (64 -> 8 per iter).
// PV also swapped (O^T = V^T·P^T) so m/l state stays per-lane aligned.
#define PSTR 40   // P row stride in bf16 (80 B)
#define ALOG2E 0.18033688011112042f   // (1/sqrt(64)) * log2(e)

__global__ __launch_bounds__(256) void attn_mfma(const bf16_t* Q,
                                                 const bf16_t* __restrict__ K,
                                                 const bf16_t* __restrict__ Vt,
                                                 bf16_t* O) {
    const int h = blockIdx.y, b = blockIdx.z;
    const int tid = threadIdx.x;
    const int wq = tid >> 6, lane = tid & 63;
    const int lo = lane & 15, quad = lane >> 4;
    const int qt = (SS / 32 - 1) - (blockIdx.x * 4 + wq);  // heavy first
    const int q0 = qt * 32;

    __shared__ bf16_t Ps[4][32 * PSTR];
    bf16_t* Pw = Ps[wq];

    // Q frags (B operand: n=q, k=dim): [sub-tile s][dim-half]
    bf16x8 qf[2][2];
#pragma unroll
    for (int s = 0; s < 2; s++)
#pragma unroll
        for (int hf = 0; hf < 2; hf++)
            qf[s][hf] = *(const bf16x8*)(Q + ((size_t)(b * SS + q0 + s * 16 + lo)) * DD +
                                         h * HD + hf * 32 + quad * 8);

    // O^T accumulators: Oacc[s][dt][reg] = O[d=dt*16+quad*4+reg][q=s*16+lo]
    floatx4 Oacc[2][4];
    float m_i[2], l_i[2];
#pragma unroll
    for (int s = 0; s < 2; s++) {
#pragma unroll
        for (int dt = 0; dt < 4; dt++) Oacc[s][dt] = (floatx4){0.f, 0.f, 0.f, 0.f};
        m_i[s] = -1e30f; l_i[s] = 0.f;
    }

    const bf16_t* Kb = K + (size_t)b * SS * HD;
    const bf16_t* Vb = Vt + (size_t)b * HD * SS;

    // K frags (A operand: m=key, k=dim), tile 0 preloaded
    bf16x8 kf[2][2];
#pragma unroll
    for (int kt = 0; kt < 2; kt++)
#pragma unroll
        for (int hf = 0; hf < 2; hf++)
            kf[kt][hf] = *(const bf16x8*)(Kb + (size_t)(kt * 16 + lo) * HD + hf * 32 + quad * 8);

    for (int it = 0; it <= qt; it++) {
        const int t0 = it * 32;

        // V frags (A operand: m=dim, k=token) — consumed after softmax
        bf16x8 vf[4];
#pragma unroll
        for (int dt = 0; dt < 4; dt++)
            vf[dt] = *(const bf16x8*)(Vb + (size_t)(dt * 16 + lo) * SS + t0 + quad * 8);

        // K prefetch for next iter
        bf16x8 kn[2][2];
        if (it < qt) {
#pragma unroll
            for (int kt = 0; kt < 2; kt++)
#pragma unroll
                for (int hf = 0; hf < 2; hf++)
                    kn[kt][hf] = *(const bf16x8*)(Kb + (size_t)(t0 + 32 + kt * 16 + lo) * HD +
                                                  hf * 32 + quad * 8);
        }

        // ---- S^T = K·Q^T: st[s][kt][reg] = S[key=t0+kt*16+quad*4+reg][q=s*16+lo]
        floatx4 st[2][2];
#pragma unroll
        for (int s = 0; s < 2; s++)
#pragma unroll
            for (int kt = 0; kt < 2; kt++) {
                floatx4 z = (floatx4){0.f, 0.f, 0.f, 0.f};
                z = __builtin_amdgcn_mfma_f32_16x16x32_bf16(kf[kt][0], qf[s][0], z, 0, 0, 0);
                z = __builtin_amdgcn_mfma_f32_16x16x32_bf16(kf[kt][1], qf[s][1], z, 0, 0, 0);
                st[s][kt] = z;
            }

        // ---- causal mask (diagonal iter only) ----
        if (it == qt) {
#pragma unroll
            for (int s = 0; s < 2; s++) {
                int q = q0 + s * 16 + lo;
#pragma unroll
                for (int kt = 0; kt < 2; kt++)
#pragma unroll
                    for (int reg = 0; reg < 4; reg++)
                        if (t0 + kt * 16 + quad * 4 + reg > q) st[s][kt][reg] = -1e30f;
            }
        }

        // ---- online softmax: per s, all 16 q-rows in parallel (lane-owned) ----
#pragma unroll
        for (int s = 0; s < 2; s++) {
            float mx = fmaxf(fmaxf(fmaxf(st[s][0][0], st[s][0][1]), fmaxf(st[s][0][2], st[s][0][3])),
                             fmaxf(fmaxf(st[s][1][0], st[s][1][1]), fmaxf(st[s][1][2], st[s][1][3])));
            mx = fmaxf(mx, __shfl_xor(mx, 16));
            mx = fmaxf(mx, __shfl_xor(mx, 32));
            float mn = fmaxf(m_i[s], mx);
            float al = exp2f((m_i[s] - mn) * ALOG2E);
            m_i[s] = mn;
            float mnA = mn * ALOG2E;
            float p[2][4];
#pragma unroll
            for (int kt = 0; kt < 2; kt++)
#pragma unroll
                for (int reg = 0; reg < 4; reg++)
                    p[kt][reg] = exp2f(st[s][kt][reg] * ALOG2E - mnA);
            float rs = ((p[0][0] + p[0][1]) + (p[0][2] + p[0][3])) +
                       ((p[1][0] + p[1][1]) + (p[1][2] + p[1][3]));
            rs += __shfl_xor(rs, 16);
            rs += __shfl_xor(rs, 32);
            l_i[s] = l_i[s] * al + rs;
            // pack 4 consecutive keys per kt -> one 8B LDS write each
#pragma unroll
            for (int kt = 0; kt < 2; kt++) {
                bf16x4 pk;
#pragma unroll
                for (int reg = 0; reg < 4; reg++) pk[reg] = (bf16_t)p[kt][reg];
                *(bf16x4*)&Pw[(s * 16 + lo) * PSTR + kt * 16 + quad * 4] = pk;
            }
#pragma unroll
            for (int dt = 0; dt < 4; dt++) Oacc[s][dt] *= al;
        }

        // wave-private LDS: drain writes (also covers shuffles), no barrier
        asm volatile("s_waitcnt lgkmcnt(0)" ::: "memory");

        // ---- O^T += V^T · P^T : B operand = P[q=lo][k=key quad*8+j] ----
        bf16x8 pb[2];
#pragma unroll
        for (int s = 0; s < 2; s++)
            pb[s] = *(const bf16x8*)&Pw[(s * 16 + lo) * PSTR + quad * 8];
#pragma unroll
        for (int s = 0; s < 2; s++)
#pragma unroll
            for (int dt = 0; dt < 4; dt++)
                Oacc[s][dt] = __builtin_amdgcn_mfma_f32_16x16x32_bf16(vf[dt], pb[s], Oacc[s][dt], 0, 0, 0);

        // rotate K double-buffer
#pragma unroll
        for (int kt = 0; kt < 2; kt++)
#pragma unroll
            for (int hf = 0; hf < 2; hf++) kf[kt][hf] = kn[kt][hf];
    }

    // ---- epilogue: normalize, write O (in-place over own Q region) ----
#pragma unroll
    for (int s = 0; s < 2; s++) {
        float inv = 1.f / l_i[s];
        bf16_t* Orow = O + ((size_t)(b * SS + q0 + s * 16 + lo)) * DD + h * HD;
#pragma unroll
        for (int dt = 0; dt < 4; dt++) {
            bf16x4 ov;
#pragma unroll
            for (int reg = 0; reg < 4; reg++) ov[reg] = (bf16_t)(Oacc[s][dt][reg] * inv);
            *(bf16x4*)&Orow[dt * 16 + quad * 4] = ov;
        }
    }
}

// ---------------- launch ----------------
extern "C" void kernel_launch(void* const* d_in, const int* in_sizes, int n_in,
                              void* d_out, int out_size, void* d_ws, size_t ws_size,
                              hipStream_t stream) {
    const void* x  = d_in[0];
    const void* Wq = d_in[1];
    const void* Wk = d_in[2];
    const void* Wv = d_in[3];
    const void* Wo = d_in[4];
    // d_in[5] = causal mask — known tril, handled analytically in attn_mfma.

    // Workspace (~9.0 MB): [flag 256B] | QA bf16[4096,1024] (Q -> attention
    // output in-place) | Kp bf16[4096,64] | VpT bf16[2][64][2048]
    char* ws = (char*)d_ws;
    int* flag = (int*)ws;
    bf16_t* QA  = (bf16_t*)(ws + 256);
    bf16_t* Kp  = QA + (size_t)MM * DD;
    bf16_t* VpT = Kp + (size_t)MM * HD;

    detect_dtype<<<1, 64, 0, stream>>>((const unsigned int*)x, flag);

    proj_qkv<<<dim3(9, MM / 128), dim3(256), 0, stream>>>(x, Wq, Wk, Wv, QA, Kp, VpT, flag);

    // Barrier-free attention: 64 wave-tasks/(b,h) in 16 blocks of 4 waves
    attn_mfma<<<dim3(SS / 32 / 4, NH, BB), dim3(256), 0, stream>>>(QA, Kp, VpT, QA);

    proj_o<<<dim3(DD / 128, MM / 128), dim3(256), 0, stream>>>(QA, Wo, d_out, flag);
}

// Round 10
// 226.070 us; speedup vs baseline: 10.6733x; 1.3026x over previous
//
#include <hip/hip_runtime.h>
#include <hip/hip_bf16.h>
#include <math.h>

// Problem constants (MultiQueryAttention: B=2, S=2048, D=1024, H=16, hd=64)
#define BB 2
#define SS 2048
#define DD 1024
#define NH 16
#define HD 64
#define MM (BB * SS)  // 4096 tokens

typedef __hip_bfloat16 bf16;      // storage type for ws tensors
typedef __bf16 bf16_t;            // native compiler bf16
typedef __attribute__((ext_vector_type(8))) __bf16 bf16x8;
typedef __attribute__((ext_vector_type(4))) __bf16 bf16x4;
typedef __attribute__((ext_vector_type(4))) float floatx4;

// ---------------- runtime dtype detection (parallel) ----------------
// flag==1 -> external tensors are fp32 (the proven world); flag==0 -> bf16.
__global__ void detect_dtype(const unsigned int* __restrict__ x, int* __restrict__ flag) {
    const int tid = threadIdx.x;  // 64 lanes
    int good = 0;
    for (int i = tid; i < 256; i += 64) {
        unsigned int bits = (x[i] & 0xFFFFu) << 16;
        float v = __uint_as_float(bits);
        float av = fabsf(v);
        if (av == 0.f || (av >= 9.5367431640625e-7f && av <= 64.f)) good++;
    }
#pragma unroll
    for (int s = 1; s < 64; s <<= 1) good += __shfl_xor(good, s);
    if (tid == 0) *flag = (good >= 240) ? 0 : 1;
}

// ---------------- MFMA projection GEMMs, register-prefetch pipelined ----------------
// 128x128 tile, BK=32, 4 waves (2x2), 16 mfma per K-iter. Global loads for
// iter k+1 are issued right after the store-barrier of iter k, so their
// latency overlaps the MFMA phase (previously: load-after-barrier = serial
// ~300-900 cyc/iter -> latency-bound at ~75 us).
#define BK 32
#define KP 40   // LDS row stride in bf16 elems

__device__ __forceinline__ bf16x4 cvt4(float4 v) {
    bf16x4 o;
    o[0] = (bf16_t)v.x; o[1] = (bf16_t)v.y; o[2] = (bf16_t)v.z; o[3] = (bf16_t)v.w;
    return o;
}

// Fused QKV projection. Q -> QA [token][1024]; K -> Kp [token][64];
// V -> VpT [b][dim][token] (transposed, for barrier-free PV A-frags).
__global__ __launch_bounds__(256) void proj_qkv(const void* __restrict__ X,
                                                const void* __restrict__ Wq,
                                                const void* __restrict__ Wk,
                                                const void* __restrict__ Wv,
                                                bf16_t* __restrict__ QA,
                                                bf16_t* __restrict__ Kp,
                                                bf16_t* __restrict__ VpT,
                                                const int* __restrict__ flag) {
    const int f = *flag;  // 1 => fp32 inputs

    __shared__ bf16_t As[128 * KP];
    __shared__ bf16_t Ws[128 * KP];

    const int tid = threadIdx.x;
    const int wave = tid >> 6, lane = tid & 63;
    const int lo = lane & 15, quad = lane >> 4;
    const int wr = wave >> 1, wc = wave & 1;
    const int cb = blockIdx.x;              // 0..8 (8 = KV block)
    const int rowBase = blockIdx.y * 128;

    floatx4 acc[4][4];
#pragma unroll
    for (int i = 0; i < 4; i++)
#pragma unroll
        for (int j = 0; j < 4; j++) acc[i][j] = (floatx4){0.f, 0.f, 0.f, 0.f};

    if (f) {
        // -------- fp32-input path --------
        const int rA = tid >> 3, sg = tid & 7;          // rows rA+32p, seg sg
        // W source row pointers (fixed per thread slot)
        const float* wrow[4];
        const float* arow[4];
#pragma unroll
        for (int p = 0; p < 4; p++) {
            int row = rA + 32 * p;
            arow[p] = (const float*)X + (size_t)(rowBase + row) * DD;
            if (cb < 8)        wrow[p] = (const float*)Wq + (size_t)(cb * 128 + row) * DD;
            else if (row < 64) wrow[p] = (const float*)Wk + (size_t)row * DD;
            else               wrow[p] = (const float*)Wv + (size_t)(row - 64) * DD;
        }
        float4 aR[4], wR[4];
#pragma unroll
        for (int p = 0; p < 4; p++) {
            aR[p] = *(const float4*)(arow[p] + sg * 4);
            wR[p] = *(const float4*)(wrow[p] + sg * 4);
        }
        for (int k0 = 0; k0 < DD; k0 += BK) {
            __syncthreads();  // prior iter's frag reads done
#pragma unroll
            for (int p = 0; p < 4; p++) {
                *(bf16x4*)&As[(rA + 32 * p) * KP + sg * 4] = cvt4(aR[p]);
                *(bf16x4*)&Ws[(rA + 32 * p) * KP + sg * 4] = cvt4(wR[p]);
            }
            __syncthreads();
            if (k0 + BK < DD) {
#pragma unroll
                for (int p = 0; p < 4; p++) {
                    aR[p] = *(const float4*)(arow[p] + k0 + BK + sg * 4);
                    wR[p] = *(const float4*)(wrow[p] + k0 + BK + sg * 4);
                }
            }
            bf16x8 afr[4], bfr[4];
#pragma unroll
            for (int i = 0; i < 4; i++)
                afr[i] = *(const bf16x8*)&As[(wr * 64 + i * 16 + lo) * KP + quad * 8];
#pragma unroll
            for (int j = 0; j < 4; j++)
                bfr[j] = *(const bf16x8*)&Ws[(wc * 64 + j * 16 + lo) * KP + quad * 8];
#pragma unroll
            for (int i = 0; i < 4; i++)
#pragma unroll
                for (int j = 0; j < 4; j++)
                    acc[i][j] = __builtin_amdgcn_mfma_f32_16x16x32_bf16(afr[i], bfr[j], acc[i][j], 0, 0, 0);
        }
    } else {
        // -------- bf16-input path --------
        const int rA = tid >> 2, sg = tid & 3;          // rows rA+64p, seg sg (8 bf16)
        const bf16_t* arow[2];
        const bf16_t* wrow[2];
#pragma unroll
        for (int p = 0; p < 2; p++) {
            int row = rA + 64 * p;
            arow[p] = (const bf16_t*)X + (size_t)(rowBase + row) * DD;
            if (cb < 8)        wrow[p] = (const bf16_t*)Wq + (size_t)(cb * 128 + row) * DD;
            else if (row < 64) wrow[p] = (const bf16_t*)Wk + (size_t)row * DD;
            else               wrow[p] = (const bf16_t*)Wv + (size_t)(row - 64) * DD;
        }
        bf16x8 aR[2], wR[2];
#pragma unroll
        for (int p = 0; p < 2; p++) {
            aR[p] = *(const bf16x8*)(arow[p] + sg * 8);
            wR[p] = *(const bf16x8*)(wrow[p] + sg * 8);
        }
        for (int k0 = 0; k0 < DD; k0 += BK) {
            __syncthreads();
#pragma unroll
            for (int p = 0; p < 2; p++) {
                *(bf16x8*)&As[(rA + 64 * p) * KP + sg * 8] = aR[p];
                *(bf16x8*)&Ws[(rA + 64 * p) * KP + sg * 8] = wR[p];
            }
            __syncthreads();
            if (k0 + BK < DD) {
#pragma unroll
                for (int p = 0; p < 2; p++) {
                    aR[p] = *(const bf16x8*)(arow[p] + k0 + BK + sg * 8);
                    wR[p] = *(const bf16x8*)(wrow[p] + k0 + BK + sg * 8);
                }
            }
            bf16x8 afr[4], bfr[4];
#pragma unroll
            for (int i = 0; i < 4; i++)
                afr[i] = *(const bf16x8*)&As[(wr * 64 + i * 16 + lo) * KP + quad * 8];
#pragma unroll
            for (int j = 0; j < 4; j++)
                bfr[j] = *(const bf16x8*)&Ws[(wc * 64 + j * 16 + lo) * KP + quad * 8];
#pragma unroll
            for (int i = 0; i < 4; i++)
#pragma unroll
                for (int j = 0; j < 4; j++)
                    acc[i][j] = __builtin_amdgcn_mfma_f32_16x16x32_bf16(afr[i], bfr[j], acc[i][j], 0, 0, 0);
        }
    }

#pragma unroll
    for (int i = 0; i < 4; i++)
#pragma unroll
        for (int j = 0; j < 4; j++)
#pragma unroll
            for (int reg = 0; reg < 4; reg++) {
                int row = rowBase + wr * 64 + i * 16 + quad * 4 + reg;  // token
                int col = wc * 64 + j * 16 + lo;
                bf16_t val = (bf16_t)acc[i][j][reg];
                if (cb < 8)         QA[(size_t)row * DD + cb * 128 + col] = val;
                else if (col < 64)  Kp[(size_t)row * HD + col] = val;
                else {
                    int d = col - 64;
                    VpT[((size_t)(row >> 11) * HD + d) * SS + (row & (SS - 1))] = val;
                }
            }
}

__global__ __launch_bounds__(256) void proj_o(const bf16_t* __restrict__ AO,
                                              const void* __restrict__ Wo,
                                              void* __restrict__ Cout,
                                              const int* __restrict__ flag) {
    const int f = *flag;

    __shared__ bf16_t As[128 * KP];
    __shared__ bf16_t Ws[128 * KP];

    const int tid = threadIdx.x;
    const int wave = tid >> 6, lane = tid & 63;
    const int lo = lane & 15, quad = lane >> 4;
    const int wr = wave >> 1, wc = wave & 1;
    const int colBase = blockIdx.x * 128;
    const int rowBase = blockIdx.y * 128;

    floatx4 acc[4][4];
#pragma unroll
    for (int i = 0; i < 4; i++)
#pragma unroll
        for (int j = 0; j < 4; j++) acc[i][j] = (floatx4){0.f, 0.f, 0.f, 0.f};

    // A staging slots (bf16 always)
    const int rA = tid >> 2, sgA = tid & 3;
    const bf16_t* arow[2] = {AO + (size_t)(rowBase + rA) * DD,
                             AO + (size_t)(rowBase + rA + 64) * DD};
    bf16x8 aR[2];
#pragma unroll
    for (int p = 0; p < 2; p++) aR[p] = *(const bf16x8*)(arow[p] + sgA * 8);

    if (f) {
        const int rW = tid >> 3, sgW = tid & 7;
        const float* wrow[4];
#pragma unroll
        for (int p = 0; p < 4; p++)
            wrow[p] = (const float*)Wo + (size_t)(colBase + rW + 32 * p) * DD;
        float4 wR[4];
#pragma unroll
        for (int p = 0; p < 4; p++) wR[p] = *(const float4*)(wrow[p] + sgW * 4);

        for (int k0 = 0; k0 < DD; k0 += BK) {
            __syncthreads();
#pragma unroll
            for (int p = 0; p < 2; p++)
                *(bf16x8*)&As[(rA + 64 * p) * KP + sgA * 8] = aR[p];
#pragma unroll
            for (int p = 0; p < 4; p++)
                *(bf16x4*)&Ws[(rW + 32 * p) * KP + sgW * 4] = cvt4(wR[p]);
            __syncthreads();
            if (k0 + BK < DD) {
#pragma unroll
                for (int p = 0; p < 2; p++)
                    aR[p] = *(const bf16x8*)(arow[p] + k0 + BK + sgA * 8);
#pragma unroll
                for (int p = 0; p < 4; p++)
                    wR[p] = *(const float4*)(wrow[p] + k0 + BK + sgW * 4);
            }
            bf16x8 afr[4], bfr[4];
#pragma unroll
            for (int i = 0; i < 4; i++)
                afr[i] = *(const bf16x8*)&As[(wr * 64 + i * 16 + lo) * KP + quad * 8];
#pragma unroll
            for (int j = 0; j < 4; j++)
                bfr[j] = *(const bf16x8*)&Ws[(wc * 64 + j * 16 + lo) * KP + quad * 8];
#pragma unroll
            for (int i = 0; i < 4; i++)
#pragma unroll
                for (int j = 0; j < 4; j++)
                    acc[i][j] = __builtin_amdgcn_mfma_f32_16x16x32_bf16(afr[i], bfr[j], acc[i][j], 0, 0, 0);
        }
    } else {
        const int rW = tid >> 2, sgW = tid & 3;
        const bf16_t* wrow[2];
#pragma unroll
        for (int p = 0; p < 2; p++)
            wrow[p] = (const bf16_t*)Wo + (size_t)(colBase + rW + 64 * p) * DD;
        bf16x8 wR[2];
#pragma unroll
        for (int p = 0; p < 2; p++) wR[p] = *(const bf16x8*)(wrow[p] + sgW * 8);

        for (int k0 = 0; k0 < DD; k0 += BK) {
            __syncthreads();
#pragma unroll
            for (int p = 0; p < 2; p++) {
                *(bf16x8*)&As[(rA + 64 * p) * KP + sgA * 8] = aR[p];
                *(bf16x8*)&Ws[(rW + 64 * p) * KP + sgW * 8] = wR[p];
            }
            __syncthreads();
            if (k0 + BK < DD) {
#pragma unroll
                for (int p = 0; p < 2; p++) {
                    aR[p] = *(const bf16x8*)(arow[p] + k0 + BK + sgA * 8);
                    wR[p] = *(const bf16x8*)(wrow[p] + k0 + BK + sgW * 8);
                }
            }
            bf16x8 afr[4], bfr[4];
#pragma unroll
            for (int i = 0; i < 4; i++)
                afr[i] = *(const bf16x8*)&As[(wr * 64 + i * 16 + lo) * KP + quad * 8];
#pragma unroll
            for (int j = 0; j < 4; j++)
                bfr[j] = *(const bf16x8*)&Ws[(wc * 64 + j * 16 + lo) * KP + quad * 8];
#pragma unroll
            for (int i = 0; i < 4; i++)
#pragma unroll
                for (int j = 0; j < 4; j++)
                    acc[i][j] = __builtin_amdgcn_mfma_f32_16x16x32_bf16(afr[i], bfr[j], acc[i][j], 0, 0, 0);
        }
    }

#pragma unroll
    for (int i = 0; i < 4; i++)
#pragma unroll
        for (int j = 0; j < 4; j++)
#pragma unroll
            for (int reg = 0; reg < 4; reg++) {
                int row = rowBase + wr * 64 + i * 16 + quad * 4 + reg;
                int col = colBase + wc * 64 + j * 16 + lo;
                size_t idx = (size_t)row * DD + col;
                if (f) ((float*)Cout)[idx] = acc[i][j][reg];
                else   ((bf16_t*)Cout)[idx] = (bf16_t)acc[i][j][reg];
            }
}

// ---------------- barrier-free MFMA flash attention, transposed scores ----------------
// One WAVE = one task: 32 q-rows of one (b,h). S^T = K.Q^T so softmax is
// in-register per lane (+2 shuffles). BALANCED block composition: block x
// hosts qt {x, 31-x, 32+x, 63-x} -> every block = 126 iter-units (R9's
// heavy-first packed the 4 heaviest waves into one block: 24:1 CU imbalance).
#define PSTR 40   // P row stride in bf16 (80 B)
#define ALOG2E 0.18033688011112042f   // (1/sqrt(64)) * log2(e)

__global__ __launch_bounds__(256) void attn_mfma(const bf16_t* Q,
                                                 const bf16_t* __restrict__ K,
                                                 const bf16_t* __restrict__ Vt,
                                                 bf16_t* O) {
    const int h = blockIdx.y, b = blockIdx.z;
    const int tid = threadIdx.x;
    const int wq = tid >> 6, lane = tid & 63;
    const int lo = lane & 15, quad = lane >> 4;
    const int x = blockIdx.x;  // 0..15
    // balanced: wq0->x, wq1->31-x, wq2->32+x, wq3->63-x
    const int qt = (wq & 1) ? (31 + (wq >> 1) * 32 - x) : ((wq >> 1) * 32 + x);
    const int q0 = qt * 32;

    __shared__ bf16_t Ps[4][32 * PSTR];
    bf16_t* Pw = Ps[wq];

    // Q frags (B operand: n=q, k=dim): [sub-tile s][dim-half]
    bf16x8 qf[2][2];
#pragma unroll
    for (int s = 0; s < 2; s++)
#pragma unroll
        for (int hf = 0; hf < 2; hf++)
            qf[s][hf] = *(const bf16x8*)(Q + ((size_t)(b * SS + q0 + s * 16 + lo)) * DD +
                                         h * HD + hf * 32 + quad * 8);

    // O^T accumulators: Oacc[s][dt][reg] = O[d=dt*16+quad*4+reg][q=s*16+lo]
    floatx4 Oacc[2][4];
    float m_i[2], l_i[2];
#pragma unroll
    for (int s = 0; s < 2; s++) {
#pragma unroll
        for (int dt = 0; dt < 4; dt++) Oacc[s][dt] = (floatx4){0.f, 0.f, 0.f, 0.f};
        m_i[s] = -1e30f; l_i[s] = 0.f;
    }

    const bf16_t* Kb = K + (size_t)b * SS * HD;
    const bf16_t* Vb = Vt + (size_t)b * HD * SS;

    // K frags (A operand: m=key, k=dim), tile 0 preloaded
    bf16x8 kf[2][2];
#pragma unroll
    for (int kt = 0; kt < 2; kt++)
#pragma unroll
        for (int hf = 0; hf < 2; hf++)
            kf[kt][hf] = *(const bf16x8*)(Kb + (size_t)(kt * 16 + lo) * HD + hf * 32 + quad * 8);

    for (int it = 0; it <= qt; it++) {
        const int t0 = it * 32;

        // V frags (A operand: m=dim, k=token) — consumed after softmax
        bf16x8 vf[4];
#pragma unroll
        for (int dt = 0; dt < 4; dt++)
            vf[dt] = *(const bf16x8*)(Vb + (size_t)(dt * 16 + lo) * SS + t0 + quad * 8);

        // K prefetch for next iter
        bf16x8 kn[2][2];
        if (it < qt) {
#pragma unroll
            for (int kt = 0; kt < 2; kt++)
#pragma unroll
                for (int hf = 0; hf < 2; hf++)
                    kn[kt][hf] = *(const bf16x8*)(Kb + (size_t)(t0 + 32 + kt * 16 + lo) * HD +
                                                  hf * 32 + quad * 8);
        }

        // ---- S^T = K.Q^T: st[s][kt][reg] = S[key=t0+kt*16+quad*4+reg][q=s*16+lo]
        floatx4 st[2][2];
#pragma unroll
        for (int s = 0; s < 2; s++)
#pragma unroll
            for (int kt = 0; kt < 2; kt++) {
                floatx4 z = (floatx4){0.f, 0.f, 0.f, 0.f};
                z = __builtin_amdgcn_mfma_f32_16x16x32_bf16(kf[kt][0], qf[s][0], z, 0, 0, 0);
                z = __builtin_amdgcn_mfma_f32_16x16x32_bf16(kf[kt][1], qf[s][1], z, 0, 0, 0);
                st[s][kt] = z;
            }

        // ---- causal mask (diagonal iter only) ----
        if (it == qt) {
#pragma unroll
            for (int s = 0; s < 2; s++) {
                int q = q0 + s * 16 + lo;
#pragma unroll
                for (int kt = 0; kt < 2; kt++)
#pragma unroll
                    for (int reg = 0; reg < 4; reg++)
                        if (t0 + kt * 16 + quad * 4 + reg > q) st[s][kt][reg] = -1e30f;
            }
        }

        // ---- online softmax: per s, all 16 q-rows in parallel (lane-owned) ----
#pragma unroll
        for (int s = 0; s < 2; s++) {
            float mx = fmaxf(fmaxf(fmaxf(st[s][0][0], st[s][0][1]), fmaxf(st[s][0][2], st[s][0][3])),
                             fmaxf(fmaxf(st[s][1][0], st[s][1][1]), fmaxf(st[s][1][2], st[s][1][3])));
            mx = fmaxf(mx, __shfl_xor(mx, 16));
            mx = fmaxf(mx, __shfl_xor(mx, 32));
            float mn = fmaxf(m_i[s], mx);
            float al = exp2f((m_i[s] - mn) * ALOG2E);
            m_i[s] = mn;
            float mnA = mn * ALOG2E;
            float p[2][4];
#pragma unroll
            for (int kt = 0; kt < 2; kt++)
#pragma unroll
                for (int reg = 0; reg < 4; reg++)
                    p[kt][reg] = exp2f(st[s][kt][reg] * ALOG2E - mnA);
            float rs = ((p[0][0] + p[0][1]) + (p[0][2] + p[0][3])) +
                       ((p[1][0] + p[1][1]) + (p[1][2] + p[1][3]));
            rs += __shfl_xor(rs, 16);
            rs += __shfl_xor(rs, 32);
            l_i[s] = l_i[s] * al + rs;
            // pack 4 consecutive keys per kt -> one 8B LDS write each
#pragma unroll
            for (int kt = 0; kt < 2; kt++) {
                bf16x4 pk;
#pragma unroll
                for (int reg = 0; reg < 4; reg++) pk[reg] = (bf16_t)p[kt][reg];
                *(bf16x4*)&Pw[(s * 16 + lo) * PSTR + kt * 16 + quad * 4] = pk;
            }
#pragma unroll
            for (int dt = 0; dt < 4; dt++) Oacc[s][dt] *= al;
        }

        // wave-private LDS: drain writes, no barrier
        asm volatile("s_waitcnt lgkmcnt(0)" ::: "memory");

        // ---- O^T += V^T . P^T : B operand = P[q=lo][k=key quad*8+j] ----
        bf16x8 pb[2];
#pragma unroll
        for (int s = 0; s < 2; s++)
            pb[s] = *(const bf16x8*)&Pw[(s * 16 + lo) * PSTR + quad * 8];
#pragma unroll
        for (int s = 0; s < 2; s++)
#pragma unroll
            for (int dt = 0; dt < 4; dt++)
                Oacc[s][dt] = __builtin_amdgcn_mfma_f32_16x16x32_bf16(vf[dt], pb[s], Oacc[s][dt], 0, 0, 0);

        // rotate K double-buffer
#pragma unroll
        for (int kt = 0; kt < 2; kt++)
#pragma unroll
            for (int hf = 0; hf < 2; hf++) kf[kt][hf] = kn[kt][hf];
    }

    // ---- epilogue: normalize, write O (in-place over own Q region) ----
#pragma unroll
    for (int s = 0; s < 2; s++) {
        float inv = 1.f / l_i[s];
        bf16_t* Orow = O + ((size_t)(b * SS + q0 + s * 16 + lo)) * DD + h * HD;
#pragma unroll
        for (int dt = 0; dt < 4; dt++) {
            bf16x4 ov;
#pragma unroll
            for (int reg = 0; reg < 4; reg++) ov[reg] = (bf16_t)(Oacc[s][dt][reg] * inv);
            *(bf16x4*)&Orow[dt * 16 + quad * 4] = ov;
        }
    }
}

// ---------------- launch ----------------
extern "C" void kernel_launch(void* const* d_in, const int* in_sizes, int n_in,
                              void* d_out, int out_size, void* d_ws, size_t ws_size,
                              hipStream_t stream) {
    const void* x  = d_in[0];
    const void* Wq = d_in[1];
    const void* Wk = d_in[2];
    const void* Wv = d_in[3];
    const void* Wo = d_in[4];
    // d_in[5] = causal mask — known tril, handled analytically in attn_mfma.

    // Workspace (~9.0 MB): [flag 256B] | QA bf16[4096,1024] (Q -> attention
    // output in-place) | Kp bf16[4096,64] | VpT bf16[2][64][2048]
    char* ws = (char*)d_ws;
    int* flag = (int*)ws;
    bf16_t* QA  = (bf16_t*)(ws + 256);
    bf16_t* Kp  = QA + (size_t)MM * DD;
    bf16_t* VpT = Kp + (size_t)MM * HD;

    detect_dtype<<<1, 64, 0, stream>>>((const unsigned int*)x, flag);

    proj_qkv<<<dim3(9, MM / 128), dim3(256), 0, stream>>>(x, Wq, Wk, Wv, QA, Kp, VpT, flag);

    // Barrier-free attention: balanced 4-wave blocks (126 iter-units each)
    attn_mfma<<<dim3(SS / 32 / 4, NH, BB), dim3(256), 0, stream>>>(QA, Kp, VpT, QA);

    proj_o<<<dim3(DD / 128, MM / 128), dim3(256), 0, stream>>>(QA, Wo, d_out, flag);
}

// Round 11
// 210.691 us; speedup vs baseline: 11.4524x; 1.0730x over previous
//
#include <hip/hip_runtime.h>
#include <hip/hip_bf16.h>
#include <math.h>

// Problem constants (MultiQueryAttention: B=2, S=2048, D=1024, H=16, hd=64)
#define BB 2
#define SS 2048
#define DD 1024
#define NH 16
#define HD 64
#define MM (BB * SS)  // 4096 tokens

typedef __hip_bfloat16 bf16;
typedef __bf16 bf16_t;
typedef __attribute__((ext_vector_type(8))) __bf16 bf16x8;
typedef __attribute__((ext_vector_type(4))) __bf16 bf16x4;
typedef __attribute__((ext_vector_type(4))) float floatx4;

// ---------------- runtime dtype detection (parallel) ----------------
// flag==1 -> external tensors are fp32 (the proven world); flag==0 -> bf16.
__global__ void detect_dtype(const unsigned int* __restrict__ x, int* __restrict__ flag) {
    const int tid = threadIdx.x;  // 64 lanes
    int good = 0;
    for (int i = tid; i < 256; i += 64) {
        unsigned int bits = (x[i] & 0xFFFFu) << 16;
        float v = __uint_as_float(bits);
        float av = fabsf(v);
        if (av == 0.f || (av >= 9.5367431640625e-7f && av <= 64.f)) good++;
    }
#pragma unroll
    for (int s = 1; s < 64; s <<= 1) good += __shfl_xor(good, s);
    if (tid == 0) *flag = (good >= 240) ? 0 : 1;
}

// ---------------- MFMA projection GEMMs ----------------
// 128(rows)x64(cols) tiles, BK=32, 4 waves (each: 32 rows x 64 cols, 8 MFMA
// per iter). Grid 2x the R10 version -> 2+ blocks/CU so cross-block overlap
// hides the staging-load latency the 1-deep prefetch can't.
#define BK 32
#define KP 40   // LDS row stride in bf16 elems

__device__ __forceinline__ bf16x4 cvt4(float4 v) {
    bf16x4 o;
    o[0] = (bf16_t)v.x; o[1] = (bf16_t)v.y; o[2] = (bf16_t)v.z; o[3] = (bf16_t)v.w;
    return o;
}

// Fused QKV projection. cb 0..15 -> QA cols cb*64..; cb 16 -> Kp; cb 17 -> VpT.
__global__ __launch_bounds__(256) void proj_qkv(const void* __restrict__ X,
                                                const void* __restrict__ Wq,
                                                const void* __restrict__ Wk,
                                                const void* __restrict__ Wv,
                                                bf16_t* __restrict__ QA,
                                                bf16_t* __restrict__ Kp,
                                                bf16_t* __restrict__ VpT,
                                                const int* __restrict__ flag) {
    const int f = *flag;  // 1 => fp32 inputs

    __shared__ bf16_t As[128 * KP];
    __shared__ bf16_t Ws[64 * KP];

    const int tid = threadIdx.x;
    const int wave = tid >> 6, lane = tid & 63;
    const int lo = lane & 15, quad = lane >> 4;
    const int rb = wave * 32;               // wave's row band
    const int cb = blockIdx.x;              // 0..17
    const int rowBase = blockIdx.y * 128;

    floatx4 acc[2][4];
#pragma unroll
    for (int i = 0; i < 2; i++)
#pragma unroll
        for (int j = 0; j < 4; j++) acc[i][j] = (floatx4){0.f, 0.f, 0.f, 0.f};

    if (f) {
        const int rA = tid >> 3, sg = tid & 7;
        const float* arow[4];
        const float* wrow[2];
#pragma unroll
        for (int p = 0; p < 4; p++)
            arow[p] = (const float*)X + (size_t)(rowBase + rA + 32 * p) * DD;
#pragma unroll
        for (int p = 0; p < 2; p++) {
            int row = rA + 32 * p;  // 0..63
            if (cb < 16)       wrow[p] = (const float*)Wq + (size_t)(cb * 64 + row) * DD;
            else if (cb == 16) wrow[p] = (const float*)Wk + (size_t)row * DD;
            else               wrow[p] = (const float*)Wv + (size_t)row * DD;
        }
        float4 aR[4], wR[2];
#pragma unroll
        for (int p = 0; p < 4; p++) aR[p] = *(const float4*)(arow[p] + sg * 4);
#pragma unroll
        for (int p = 0; p < 2; p++) wR[p] = *(const float4*)(wrow[p] + sg * 4);

        for (int k0 = 0; k0 < DD; k0 += BK) {
            __syncthreads();
#pragma unroll
            for (int p = 0; p < 4; p++)
                *(bf16x4*)&As[(rA + 32 * p) * KP + sg * 4] = cvt4(aR[p]);
#pragma unroll
            for (int p = 0; p < 2; p++)
                *(bf16x4*)&Ws[(rA + 32 * p) * KP + sg * 4] = cvt4(wR[p]);
            __syncthreads();
            if (k0 + BK < DD) {
#pragma unroll
                for (int p = 0; p < 4; p++) aR[p] = *(const float4*)(arow[p] + k0 + BK + sg * 4);
#pragma unroll
                for (int p = 0; p < 2; p++) wR[p] = *(const float4*)(wrow[p] + k0 + BK + sg * 4);
            }
            bf16x8 afr[2], bfr[4];
#pragma unroll
            for (int i = 0; i < 2; i++)
                afr[i] = *(const bf16x8*)&As[(rb + i * 16 + lo) * KP + quad * 8];
#pragma unroll
            for (int j = 0; j < 4; j++)
                bfr[j] = *(const bf16x8*)&Ws[(j * 16 + lo) * KP + quad * 8];
#pragma unroll
            for (int i = 0; i < 2; i++)
#pragma unroll
                for (int j = 0; j < 4; j++)
                    acc[i][j] = __builtin_amdgcn_mfma_f32_16x16x32_bf16(afr[i], bfr[j], acc[i][j], 0, 0, 0);
        }
    } else {
        const int rA = tid >> 2, sg = tid & 3;   // rA 0..63
        const bf16_t* arow[2];
        const bf16_t* wrow;
#pragma unroll
        for (int p = 0; p < 2; p++)
            arow[p] = (const bf16_t*)X + (size_t)(rowBase + rA + 64 * p) * DD;
        if (cb < 16)       wrow = (const bf16_t*)Wq + (size_t)(cb * 64 + rA) * DD;
        else if (cb == 16) wrow = (const bf16_t*)Wk + (size_t)rA * DD;
        else               wrow = (const bf16_t*)Wv + (size_t)rA * DD;
        bf16x8 aR[2], wR;
#pragma unroll
        for (int p = 0; p < 2; p++) aR[p] = *(const bf16x8*)(arow[p] + sg * 8);
        wR = *(const bf16x8*)(wrow + sg * 8);

        for (int k0 = 0; k0 < DD; k0 += BK) {
            __syncthreads();
#pragma unroll
            for (int p = 0; p < 2; p++)
                *(bf16x8*)&As[(rA + 64 * p) * KP + sg * 8] = aR[p];
            *(bf16x8*)&Ws[rA * KP + sg * 8] = wR;
            __syncthreads();
            if (k0 + BK < DD) {
#pragma unroll
                for (int p = 0; p < 2; p++) aR[p] = *(const bf16x8*)(arow[p] + k0 + BK + sg * 8);
                wR = *(const bf16x8*)(wrow + k0 + BK + sg * 8);
            }
            bf16x8 afr[2], bfr[4];
#pragma unroll
            for (int i = 0; i < 2; i++)
                afr[i] = *(const bf16x8*)&As[(rb + i * 16 + lo) * KP + quad * 8];
#pragma unroll
            for (int j = 0; j < 4; j++)
                bfr[j] = *(const bf16x8*)&Ws[(j * 16 + lo) * KP + quad * 8];
#pragma unroll
            for (int i = 0; i < 2; i++)
#pragma unroll
                for (int j = 0; j < 4; j++)
                    acc[i][j] = __builtin_amdgcn_mfma_f32_16x16x32_bf16(afr[i], bfr[j], acc[i][j], 0, 0, 0);
        }
    }

#pragma unroll
    for (int i = 0; i < 2; i++)
#pragma unroll
        for (int j = 0; j < 4; j++)
#pragma unroll
            for (int reg = 0; reg < 4; reg++) {
                int row = rowBase + rb + i * 16 + quad * 4 + reg;  // token
                int col = j * 16 + lo;                              // 0..63
                bf16_t val = (bf16_t)acc[i][j][reg];
                if (cb < 16)       QA[(size_t)row * DD + cb * 64 + col] = val;
                else if (cb == 16) Kp[(size_t)row * HD + col] = val;
                else               VpT[((size_t)(row >> 11) * HD + col) * SS + (row & (SS - 1))] = val;
            }
}

__global__ __launch_bounds__(256) void proj_o(const bf16_t* __restrict__ AO,
                                              const void* __restrict__ Wo,
                                              void* __restrict__ Cout,
                                              const int* __restrict__ flag) {
    const int f = *flag;

    __shared__ bf16_t As[128 * KP];
    __shared__ bf16_t Ws[64 * KP];

    const int tid = threadIdx.x;
    const int wave = tid >> 6, lane = tid & 63;
    const int lo = lane & 15, quad = lane >> 4;
    const int rb = wave * 32;
    const int colBase = blockIdx.x * 64;
    const int rowBase = blockIdx.y * 128;

    floatx4 acc[2][4];
#pragma unroll
    for (int i = 0; i < 2; i++)
#pragma unroll
        for (int j = 0; j < 4; j++) acc[i][j] = (floatx4){0.f, 0.f, 0.f, 0.f};

    // A staging (bf16 always)
    const int rA2 = tid >> 2, sgA = tid & 3;
    const bf16_t* arow[2] = {AO + (size_t)(rowBase + rA2) * DD,
                             AO + (size_t)(rowBase + rA2 + 64) * DD};
    bf16x8 aR[2];
#pragma unroll
    for (int p = 0; p < 2; p++) aR[p] = *(const bf16x8*)(arow[p] + sgA * 8);

    if (f) {
        const int rW = tid >> 3, sgW = tid & 7;
        const float* wrow[2];
#pragma unroll
        for (int p = 0; p < 2; p++)
            wrow[p] = (const float*)Wo + (size_t)(colBase + rW + 32 * p) * DD;
        float4 wR[2];
#pragma unroll
        for (int p = 0; p < 2; p++) wR[p] = *(const float4*)(wrow[p] + sgW * 4);

        for (int k0 = 0; k0 < DD; k0 += BK) {
            __syncthreads();
#pragma unroll
            for (int p = 0; p < 2; p++)
                *(bf16x8*)&As[(rA2 + 64 * p) * KP + sgA * 8] = aR[p];
#pragma unroll
            for (int p = 0; p < 2; p++)
                *(bf16x4*)&Ws[(rW + 32 * p) * KP + sgW * 4] = cvt4(wR[p]);
            __syncthreads();
            if (k0 + BK < DD) {
#pragma unroll
                for (int p = 0; p < 2; p++) aR[p] = *(const bf16x8*)(arow[p] + k0 + BK + sgA * 8);
#pragma unroll
                for (int p = 0; p < 2; p++) wR[p] = *(const float4*)(wrow[p] + k0 + BK + sgW * 4);
            }
            bf16x8 afr[2], bfr[4];
#pragma unroll
            for (int i = 0; i < 2; i++)
                afr[i] = *(const bf16x8*)&As[(rb + i * 16 + lo) * KP + quad * 8];
#pragma unroll
            for (int j = 0; j < 4; j++)
                bfr[j] = *(const bf16x8*)&Ws[(j * 16 + lo) * KP + quad * 8];
#pragma unroll
            for (int i = 0; i < 2; i++)
#pragma unroll
                for (int j = 0; j < 4; j++)
                    acc[i][j] = __builtin_amdgcn_mfma_f32_16x16x32_bf16(afr[i], bfr[j], acc[i][j], 0, 0, 0);
        }
    } else {
        const bf16_t* wrow = (const bf16_t*)Wo + (size_t)(colBase + rA2) * DD;
        bf16x8 wR = *(const bf16x8*)(wrow + sgA * 8);

        for (int k0 = 0; k0 < DD; k0 += BK) {
            __syncthreads();
#pragma unroll
            for (int p = 0; p < 2; p++)
                *(bf16x8*)&As[(rA2 + 64 * p) * KP + sgA * 8] = aR[p];
            *(bf16x8*)&Ws[rA2 * KP + sgA * 8] = wR;
            __syncthreads();
            if (k0 + BK < DD) {
#pragma unroll
                for (int p = 0; p < 2; p++) aR[p] = *(const bf16x8*)(arow[p] + k0 + BK + sgA * 8);
                wR = *(const bf16x8*)(wrow + k0 + BK + sgA * 8);
            }
            bf16x8 afr[2], bfr[4];
#pragma unroll
            for (int i = 0; i < 2; i++)
                afr[i] = *(const bf16x8*)&As[(rb + i * 16 + lo) * KP + quad * 8];
#pragma unroll
            for (int j = 0; j < 4; j++)
                bfr[j] = *(const bf16x8*)&Ws[(j * 16 + lo) * KP + quad * 8];
#pragma unroll
            for (int i = 0; i < 2; i++)
#pragma unroll
                for (int j = 0; j < 4; j++)
                    acc[i][j] = __builtin_amdgcn_mfma_f32_16x16x32_bf16(afr[i], bfr[j], acc[i][j], 0, 0, 0);
        }
    }

#pragma unroll
    for (int i = 0; i < 2; i++)
#pragma unroll
        for (int j = 0; j < 4; j++)
#pragma unroll
            for (int reg = 0; reg < 4; reg++) {
                int row = rowBase + rb + i * 16 + quad * 4 + reg;
                int col = colBase + j * 16 + lo;
                size_t idx = (size_t)row * DD + col;
                if (f) ((float*)Cout)[idx] = acc[i][j][reg];
                else   ((bf16_t*)Cout)[idx] = (bf16_t)acc[i][j][reg];
            }
}

// ---------------- barrier-free MFMA flash attention, key-split ----------------
// One wave = 32 q-rows of one (b,h) x HALF the key range. Block = 4 waves =
// q-tiles {x, 63-x} x 2 key-halves -> 1024 blocks (4/CU), every block exactly
// 65 iter-units. S^T = K.Q^T keeps softmax in-register. Halves merge (m,l,O^T)
// through LDS with a single block barrier (standard flash merge algebra).
#define PSTR 40
#define ALOG2E 0.18033688011112042f   // (1/sqrt(64)) * log2(e)

__global__ __launch_bounds__(256, 4) void attn_mfma(const bf16_t* Q,
                                                    const bf16_t* __restrict__ K,
                                                    const bf16_t* __restrict__ Vt,
                                                    bf16_t* O) {
    const int h = blockIdx.y, b = blockIdx.z;
    const int tid = threadIdx.x;
    const int wq = tid >> 6, lane = tid & 63;
    const int lo = lane & 15, quad = lane >> 4;
    const int x = blockIdx.x;           // 0..31
    const int pr = wq >> 1;             // pair id: qt = x or 63-x
    const int hh = wq & 1;              // key-half
    const int qt = pr ? (63 - x) : x;
    const int q0 = qt * 32;
    const int nt = qt + 1;              // total 32-key tiles for this q-tile
    const int nt0 = nt >> 1;
    const int itS = hh ? nt0 : 0;
    const int itE = hh ? nt : nt0;

    __shared__ bf16_t Ps[4][32 * PSTR];        // P staging, wave-private
    __shared__ float MrgO[2][32][64];          // [pair][valIdx][lane]
    __shared__ float MrgML[2][2][2][16];       // [pair][s][m/l][lo]
    bf16_t* Pw = Ps[wq];

    // Q frags (B operand: n=q, k=dim)
    bf16x8 qf[2][2];
#pragma unroll
    for (int s = 0; s < 2; s++)
#pragma unroll
        for (int hf = 0; hf < 2; hf++)
            qf[s][hf] = *(const bf16x8*)(Q + ((size_t)(b * SS + q0 + s * 16 + lo)) * DD +
                                         h * HD + hf * 32 + quad * 8);

    floatx4 Oacc[2][4];
    float m_i[2], l_i[2];
#pragma unroll
    for (int s = 0; s < 2; s++) {
#pragma unroll
        for (int dt = 0; dt < 4; dt++) Oacc[s][dt] = (floatx4){0.f, 0.f, 0.f, 0.f};
        m_i[s] = -1e30f; l_i[s] = 0.f;
    }

    const bf16_t* Kb = K + (size_t)b * SS * HD;
    const bf16_t* Vb = Vt + (size_t)b * HD * SS;

    if (itS < itE) {
        // preload K tile itS
        bf16x8 kf[2][2];
#pragma unroll
        for (int kt = 0; kt < 2; kt++)
#pragma unroll
            for (int hf = 0; hf < 2; hf++)
                kf[kt][hf] = *(const bf16x8*)(Kb + (size_t)(itS * 32 + kt * 16 + lo) * HD +
                                              hf * 32 + quad * 8);

        for (int it = itS; it < itE; it++) {
            const int t0 = it * 32;

            bf16x8 vf[4];
#pragma unroll
            for (int dt = 0; dt < 4; dt++)
                vf[dt] = *(const bf16x8*)(Vb + (size_t)(dt * 16 + lo) * SS + t0 + quad * 8);

            bf16x8 kn[2][2];
            if (it + 1 < itE) {
#pragma unroll
                for (int kt = 0; kt < 2; kt++)
#pragma unroll
                    for (int hf = 0; hf < 2; hf++)
                        kn[kt][hf] = *(const bf16x8*)(Kb + (size_t)(t0 + 32 + kt * 16 + lo) * HD +
                                                      hf * 32 + quad * 8);
            }

            // S^T = K.Q^T
            floatx4 st[2][2];
#pragma unroll
            for (int s = 0; s < 2; s++)
#pragma unroll
                for (int kt = 0; kt < 2; kt++) {
                    floatx4 z = (floatx4){0.f, 0.f, 0.f, 0.f};
                    z = __builtin_amdgcn_mfma_f32_16x16x32_bf16(kf[kt][0], qf[s][0], z, 0, 0, 0);
                    z = __builtin_amdgcn_mfma_f32_16x16x32_bf16(kf[kt][1], qf[s][1], z, 0, 0, 0);
                    st[s][kt] = z;
                }

            if (it == qt) {  // diagonal tile (always in the upper half-wave)
#pragma unroll
                for (int s = 0; s < 2; s++) {
                    int q = q0 + s * 16 + lo;
#pragma unroll
                    for (int kt = 0; kt < 2; kt++)
#pragma unroll
                        for (int reg = 0; reg < 4; reg++)
                            if (t0 + kt * 16 + quad * 4 + reg > q) st[s][kt][reg] = -1e30f;
                }
            }

            // online softmax, lane-owned q-rows
#pragma unroll
            for (int s = 0; s < 2; s++) {
                float mx = fmaxf(fmaxf(fmaxf(st[s][0][0], st[s][0][1]), fmaxf(st[s][0][2], st[s][0][3])),
                                 fmaxf(fmaxf(st[s][1][0], st[s][1][1]), fmaxf(st[s][1][2], st[s][1][3])));
                mx = fmaxf(mx, __shfl_xor(mx, 16));
                mx = fmaxf(mx, __shfl_xor(mx, 32));
                float mn = fmaxf(m_i[s], mx);
                float al = exp2f((m_i[s] - mn) * ALOG2E);
                m_i[s] = mn;
                float mnA = mn * ALOG2E;
                float p[2][4];
#pragma unroll
                for (int kt = 0; kt < 2; kt++)
#pragma unroll
                    for (int reg = 0; reg < 4; reg++)
                        p[kt][reg] = exp2f(st[s][kt][reg] * ALOG2E - mnA);
                float rs = ((p[0][0] + p[0][1]) + (p[0][2] + p[0][3])) +
                           ((p[1][0] + p[1][1]) + (p[1][2] + p[1][3]));
                rs += __shfl_xor(rs, 16);
                rs += __shfl_xor(rs, 32);
                l_i[s] = l_i[s] * al + rs;
#pragma unroll
                for (int kt = 0; kt < 2; kt++) {
                    bf16x4 pk;
#pragma unroll
                    for (int reg = 0; reg < 4; reg++) pk[reg] = (bf16_t)p[kt][reg];
                    *(bf16x4*)&Pw[(s * 16 + lo) * PSTR + kt * 16 + quad * 4] = pk;
                }
#pragma unroll
                for (int dt = 0; dt < 4; dt++) Oacc[s][dt] *= al;
            }

            asm volatile("s_waitcnt lgkmcnt(0)" ::: "memory");

            // O^T += V^T . P^T
            bf16x8 pb[2];
#pragma unroll
            for (int s = 0; s < 2; s++)
                pb[s] = *(const bf16x8*)&Pw[(s * 16 + lo) * PSTR + quad * 8];
#pragma unroll
            for (int s = 0; s < 2; s++)
#pragma unroll
                for (int dt = 0; dt < 4; dt++)
                    Oacc[s][dt] = __builtin_amdgcn_mfma_f32_16x16x32_bf16(vf[dt], pb[s], Oacc[s][dt], 0, 0, 0);

#pragma unroll
            for (int kt = 0; kt < 2; kt++)
#pragma unroll
                for (int hf = 0; hf < 2; hf++) kf[kt][hf] = kn[kt][hf];
        }
    }

    // ---- merge halves: upper half publishes partial; lower half combines ----
    if (hh) {
#pragma unroll
        for (int s = 0; s < 2; s++) {
#pragma unroll
            for (int dt = 0; dt < 4; dt++)
#pragma unroll
                for (int reg = 0; reg < 4; reg++)
                    MrgO[pr][s * 16 + dt * 4 + reg][lane] = Oacc[s][dt][reg];
            if (quad == 0) {
                MrgML[pr][s][0][lo] = m_i[s];
                MrgML[pr][s][1][lo] = l_i[s];
            }
        }
    }
    __syncthreads();
    if (!hh) {
#pragma unroll
        for (int s = 0; s < 2; s++) {
            float m1 = MrgML[pr][s][0][lo];
            float l1 = MrgML[pr][s][1][lo];
            float mm = fmaxf(m_i[s], m1);
            float a0 = exp2f((m_i[s] - mm) * ALOG2E);
            float a1 = exp2f((m1 - mm) * ALOG2E);
            float linv = 1.f / (l_i[s] * a0 + l1 * a1);
            bf16_t* Orow = O + ((size_t)(b * SS + q0 + s * 16 + lo)) * DD + h * HD;
#pragma unroll
            for (int dt = 0; dt < 4; dt++) {
                bf16x4 ov;
#pragma unroll
                for (int reg = 0; reg < 4; reg++) {
                    float o1 = MrgO[pr][s * 16 + dt * 4 + reg][lane];
                    ov[reg] = (bf16_t)((Oacc[s][dt][reg] * a0 + o1 * a1) * linv);
                }
                *(bf16x4*)&Orow[dt * 16 + quad * 4] = ov;
            }
        }
    }
}

// ---------------- launch ----------------
extern "C" void kernel_launch(void* const* d_in, const int* in_sizes, int n_in,
                              void* d_out, int out_size, void* d_ws, size_t ws_size,
                              hipStream_t stream) {
    const void* x  = d_in[0];
    const void* Wq = d_in[1];
    const void* Wk = d_in[2];
    const void* Wv = d_in[3];
    const void* Wo = d_in[4];
    // d_in[5] = causal mask — known tril, handled analytically in attn_mfma.

    // Workspace (~9.0 MB): [flag 256B] | QA bf16[4096,1024] (Q -> attention
    // output in-place) | Kp bf16[4096,64] | VpT bf16[2][64][2048]
    char* ws = (char*)d_ws;
    int* flag = (int*)ws;
    bf16_t* QA  = (bf16_t*)(ws + 256);
    bf16_t* Kp  = QA + (size_t)MM * DD;
    bf16_t* VpT = Kp + (size_t)MM * HD;

    detect_dtype<<<1, 64, 0, stream>>>((const unsigned int*)x, flag);

    // 128x64 tiles: 18x32 = 576 blocks (~2.25/CU)
    proj_qkv<<<dim3(18, MM / 128), dim3(256), 0, stream>>>(x, Wq, Wk, Wv, QA, Kp, VpT, flag);

    // Key-split attention: 32 pair-blocks x NH x BB = 1024 blocks (4/CU)
    attn_mfma<<<dim3(32, NH, BB), dim3(256), 0, stream>>>(QA, Kp, VpT, QA);

    // 128x64 tiles: 16x32 = 512 blocks (2/CU)
    proj_o<<<dim3(16, MM / 128), dim3(256), 0, stream>>>(QA, Wo, d_out, flag);
}